// Round 2
// baseline (3847.203 us; speedup 1.0000x reference)
//
#include <hip/hip_runtime.h>
#include <math.h>

#define DINL __device__ __forceinline__

// ---------------- geometry ----------------
// image: [1536][48][72]
// conv1: -> [32][23][35]  (805 spatial)
// conv2: -> [64][11][17]  (187 spatial), stored as [n][sp][oc]
// conv3: -> [32][5][8]    (40 spatial) -> feat 1280, + rel_pos 3 -> 1283
// LTC: UNITS=48, ODE_UNFOLDS=6, S=48, B=32

static constexpr int O_OUT2 = 0;                         // [1536][187][64]
static constexpr int O_X    = O_OUT2 + 1536 * 187 * 64;  // [1536][1283]
static constexpr int O_WNUM = O_X + 1536 * 1283;         // [1536][48]
static constexpr int O_WDEN = O_WNUM + 1536 * 48;
static constexpr int O_SSIG = O_WDEN + 1536 * 48;        // [48][1283] transposed
static constexpr int O_SMU  = O_SSIG + 48 * 1283;
static constexpr int O_SW   = O_SMU + 48 * 1283;
static constexpr int O_SWE  = O_SW + 48 * 1283;
static constexpr int O_WM   = O_SWE + 48 * 1283;         // [48][48] w_syn*mask
static constexpr int O_WME  = O_WM + 48 * 48;            // [48][48] w_syn*mask*erev
static constexpr int O_W1T  = O_WME + 48 * 48;           // [32][9][64]: [c][k][oc]
static constexpr int O_W2T  = O_W1T + 32 * 9 * 64;       // [32][9][64]: [oc][k][c]

DINL float sigmoid_f(float z) {
  return __builtin_amdgcn_rcpf(1.f + __expf(-z));
}

// -------- pre: transpose sensory params to [j][i], fold mask & erev --------
__global__ void k_pre_sensory(const float* ssig, const float* smu, const float* sw,
                              const float* serev, const int* smask,
                              float* o_sig, float* o_mu, float* o_w, float* o_we) {
  int idx = blockIdx.x * 256 + threadIdx.x;
  if (idx >= 1283 * 48) return;
  int i = idx / 48, j = idx - i * 48;
  float m  = (float)smask[idx];
  float w  = sw[idx] * m;
  int o = j * 1283 + i;
  o_sig[o] = ssig[idx];
  o_mu[o]  = smu[idx];
  o_w[o]   = w;
  o_we[o]  = w * serev[idx];
}

// -------- pre: recurrent params, fold mask & erev (keep [i][j]) --------
__global__ void k_pre_rec(const float* w_syn, const float* erev, const int* mask,
                          float* o_wm, float* o_wme) {
  int idx = blockIdx.x * 256 + threadIdx.x;
  if (idx >= 48 * 48) return;
  float wm = w_syn[idx] * (float)mask[idx];
  o_wm[idx]  = wm;
  o_wme[idx] = wm * erev[idx];
}

// -------- pre: weight transposes for coalesced loads --------
__global__ void k_pre_w(const float* w1, const float* w2, float* w1t, float* w2t) {
  int idx = blockIdx.x * 256 + threadIdx.x;
  if (idx < 18432) {          // w1 [64][32][9] -> [c][k][oc]
    int oc = idx / 288;
    int rem = idx - oc * 288;
    int c = rem / 9, k = rem - c * 9;
    w1t[(c * 9 + k) * 64 + oc] = w1[idx];
  } else if (idx < 36864) {   // w2 [32][64][9] -> [oc][k][c]
    int i2 = idx - 18432;
    int oc = i2 / 576;
    int rem = i2 - oc * 576;
    int c = rem / 9, k = rem - c * 9;
    w2t[oc * 576 + k * 64 + c] = w2[i2];
  }
}

// -------- fused conv1 + conv2, one block per image, channel-sliced --------
// LDS: simg 3456 + sw0 288 + sb0 32 + sc1g 4*828 + sw1g 4*9*64 = 9392 fl
//      = 37.6 KB -> 4 blocks/CU -> 16 waves/CU
__global__ __launch_bounds__(256, 4) void k_conv12(const float* __restrict__ gimg,
        const float* __restrict__ w0, const float* __restrict__ b0,
        const float* __restrict__ w1t, const float* __restrict__ b1,
        float* __restrict__ gout2) {
  __shared__ float simg[3456];
  __shared__ float sw0[288];
  __shared__ float sb0[32];
  __shared__ float sc1g[4 * 828];   // 4 channels x [23][36] (36: 8B-aligned rows)
  __shared__ float sw1g[4 * 9 * 64];
  const int n = blockIdx.x, t = threadIdx.x;

  const float* gi = gimg + n * 3456;
  for (int k = t; k < 3456; k += 256) simg[k] = gi[k];
  for (int k = t; k < 288; k += 256) sw0[k] = w0[k];
  if (t < 32) sb0[t] = b0[t];

  // conv2 accumulators: thread = (ocq, g); oc in {ocq+16m}, sp = q*16+g
  const int ocq = t & 15, g = t >> 4;
  float acc[12][4];
  int rowb[12];
#pragma unroll
  for (int m = 0; m < 4; ++m) {
    float bb = b1[ocq + 16 * m];
#pragma unroll
    for (int q = 0; q < 12; ++q) acc[q][m] = bb;
  }
#pragma unroll
  for (int q = 0; q < 12; ++q) {
    int sp = q * 16 + g; if (sp > 186) sp = 186;
    int oh = sp / 17, ow = sp - oh * 17;
    rowb[q] = (2 * oh) * 36 + 2 * ow;
  }
  __syncthreads();

  for (int grp = 0; grp < 8; ++grp) {
    // stage w1 slice [4c][9k][64oc]
    for (int k = t; k < 2304; k += 256) sw1g[k] = w1t[grp * 2304 + k];
    // conv1 for channels 4*grp .. 4*grp+3
    for (int idx = t; idx < 3220; idx += 256) {
      int c4 = idx / 805, sp = idx - c4 * 805;
      int oh = sp / 35, ow = sp - oh * 35;
      const float* ip = simg + (2 * oh) * 72 + 2 * ow;
      const float* wp = sw0 + (grp * 4 + c4) * 9;
      float a = sb0[grp * 4 + c4];
#pragma unroll
      for (int kh = 0; kh < 3; ++kh)
        a += ip[kh * 72 + 0] * wp[kh * 3 + 0] + ip[kh * 72 + 1] * wp[kh * 3 + 1]
           + ip[kh * 72 + 2] * wp[kh * 3 + 2];
      sc1g[c4 * 828 + oh * 36 + ow] = fmaxf(a, 0.f);
    }
    __syncthreads();

#pragma unroll
    for (int c4 = 0; c4 < 4; ++c4) {
      float wr[4][9];
#pragma unroll
      for (int k = 0; k < 9; ++k)
#pragma unroll
        for (int m = 0; m < 4; ++m) wr[m][k] = sw1g[(c4 * 9 + k) * 64 + ocq + 16 * m];
      const float* cb = sc1g + c4 * 828;
#pragma unroll
      for (int q = 0; q < 12; ++q) {
        const float* p = cb + rowb[q];
#pragma unroll
        for (int kh = 0; kh < 3; ++kh) {
          float x0 = p[kh * 36], x1 = p[kh * 36 + 1], x2 = p[kh * 36 + 2];
#pragma unroll
          for (int m = 0; m < 4; ++m)
            acc[q][m] += x0 * wr[m][kh * 3] + x1 * wr[m][kh * 3 + 1] + x2 * wr[m][kh * 3 + 2];
        }
      }
    }
    __syncthreads();
  }

  float* go = gout2 + n * 11968;
#pragma unroll
  for (int q = 0; q < 12; ++q) {
    int sp = q * 16 + g;
    if (sp < 187)
#pragma unroll
      for (int m = 0; m < 4; ++m)
        go[sp * 64 + ocq + 16 * m] = fmaxf(acc[q][m], 0.f);
  }
}

// -------- conv3 + concat, one block per image, channel-sliced --------
// LDS: sin2g [187][17]=3179 + sw2g [32][145]=4640 + 32 = 31.4 KB -> 5 blk/CU
__global__ __launch_bounds__(256, 5) void k_conv3(const float* __restrict__ gout2,
        const float* __restrict__ w2t, const float* __restrict__ b2,
        const float* __restrict__ grel, float* __restrict__ gx) {
  __shared__ float sin2g[187 * 17];   // [sp_in][c16], row pad 17
  __shared__ float sw2g[32 * 145];    // [oc][9k*16c], oc stride 145 (17*oc mod 32 distinct)
  const int n = blockIdx.x, t = threadIdx.x;
  const float* gi = gout2 + n * 11968;

  const int oc = t & 15, g = t >> 4;   // oc handles {oc, oc+16}; sp = q*16+g
  float acc[3][2];
  int rowb[3];
#pragma unroll
  for (int q = 0; q < 3; ++q) {
    acc[q][0] = b2[oc]; acc[q][1] = b2[oc + 16];
    int sp = q * 16 + g; if (sp > 39) sp = 39;
    int oh = sp >> 3, ow = sp & 7;
    rowb[q] = ((2 * oh) * 17 + 2 * ow) * 17;   // input spatial base * row-pad
  }

  for (int grp = 0; grp < 4; ++grp) {
    // stage input channel slice [187 sp][16 c]
    for (int idx = t; idx < 2992; idx += 256) {
      int sp = idx >> 4, c = idx & 15;
      sin2g[sp * 17 + c] = gi[sp * 64 + grp * 16 + c];
    }
    // stage weight slice [32 oc][9k x 16c]
    for (int idx = t; idx < 4608; idx += 256) {
      int oc2 = idx / 144, r = idx - oc2 * 144;  // r = k*16 + c
      sw2g[oc2 * 145 + r] = w2t[oc2 * 576 + (r >> 4) * 64 + grp * 16 + (r & 15)];
    }
    __syncthreads();

    for (int c = 0; c < 16; ++c) {
      float wr0[9], wr1[9];
#pragma unroll
      for (int k = 0; k < 9; ++k) {
        wr0[k] = sw2g[oc * 145 + k * 16 + c];
        wr1[k] = sw2g[(oc + 16) * 145 + k * 16 + c];
      }
#pragma unroll
      for (int q = 0; q < 3; ++q) {
        const float* p = sin2g + rowb[q] + c;
#pragma unroll
        for (int kh = 0; kh < 3; ++kh) {
          float x0 = p[kh * 289], x1 = p[kh * 289 + 17], x2 = p[kh * 289 + 34];
          acc[q][0] += x0 * wr0[3 * kh] + x1 * wr0[3 * kh + 1] + x2 * wr0[3 * kh + 2];
          acc[q][1] += x0 * wr1[3 * kh] + x1 * wr1[3 * kh + 1] + x2 * wr1[3 * kh + 2];
        }
      }
    }
    __syncthreads();
  }

  float* xo = gx + n * 1283;
#pragma unroll
  for (int q = 0; q < 3; ++q) {
    int sp = q * 16 + g;
    if (sp < 40) {
      xo[oc * 40 + sp]        = fmaxf(acc[q][0], 0.f);
      xo[(oc + 16) * 40 + sp] = fmaxf(acc[q][1], 0.f);
    }
  }
  if (t < 3) xo[1280 + t] = grel[n * 3 + t];
}

// -------- sensory synapse sums: 8 time-slots per block --------
__global__ __launch_bounds__(256) void k_sensory(const float* __restrict__ gx,
        const float* __restrict__ iw, const float* __restrict__ ib,
        const float* __restrict__ psig, const float* __restrict__ pmu,
        const float* __restrict__ pw, const float* __restrict__ pwe,
        float* __restrict__ wnum, float* __restrict__ wden) {
  __shared__ float xs[8 * 1283];
  const int t = threadIdx.x;
  const int bs0 = blockIdx.x * 8;
  for (int idx = t; idx < 8 * 1283; idx += 256) {
    int slot = idx / 1283, i = idx - slot * 1283;
    xs[idx] = gx[(bs0 + slot) * 1283 + i] * iw[i] + ib[i];
  }
  __syncthreads();
  const int w = t >> 6, l = t & 63;
  for (int jj = 0; jj < 12; ++jj) {
    int j = w * 12 + jj;
    const float* pa = psig + j * 1283;
    const float* pm = pmu + j * 1283;
    const float* pww = pw + j * 1283;
    const float* pe = pwe + j * 1283;
    float an[8], ad[8];
#pragma unroll
    for (int s2 = 0; s2 < 8; ++s2) { an[s2] = 0.f; ad[s2] = 0.f; }
    for (int i = l; i < 1283; i += 64) {
      float a = pa[i], m = pm[i], ww = pww[i], we = pe[i];
#pragma unroll
      for (int s2 = 0; s2 < 8; ++s2) {
        float sg = sigmoid_f((xs[s2 * 1283 + i] - m) * a);
        an[s2] += we * sg;
        ad[s2] += ww * sg;
      }
    }
#pragma unroll
    for (int off = 32; off; off >>= 1)
#pragma unroll
      for (int s2 = 0; s2 < 8; ++s2) {
        an[s2] += __shfl_xor(an[s2], off);
        ad[s2] += __shfl_xor(ad[s2], off);
      }
    if (l == 0) {
#pragma unroll
      for (int s2 = 0; s2 < 8; ++s2) {
        wnum[(bs0 + s2) * 48 + j] = an[s2];
        wden[(bs0 + s2) * 48 + j] = ad[s2];
      }
    }
  }
}

// -------- LTC scan: one block per batch, 48 posts x 8 pre-groups --------
__global__ __launch_bounds__(384) void k_scan(const float* __restrict__ gmu,
        const float* __restrict__ gsig, const float* __restrict__ wm,
        const float* __restrict__ wme, const float* __restrict__ wnum,
        const float* __restrict__ wden, const float* __restrict__ gleak,
        const float* __restrict__ vleak, const float* __restrict__ cm,
        const float* __restrict__ w_out, const float* __restrict__ b_out,
        const float* __restrict__ w_head, const float* __restrict__ b_head,
        float* __restrict__ out) {
  __shared__ float smu[48 * 49], ssg[48 * 49], swm[48 * 49], swe[48 * 49];
  __shared__ float vbuf[2][48];
  __shared__ float m4[4];
  const int t = threadIdx.x, b = blockIdx.x;
  for (int idx = t; idx < 2304; idx += 384) {
    int i = idx / 48, jx = idx - i * 48;
    int o = i * 49 + jx;
    smu[o] = gmu[idx]; ssg[o] = gsig[idx];
    swm[o] = wm[idx];  swe[o] = wme[idx];
  }
  if (t < 48) { vbuf[0][t] = 0.f; vbuf[1][t] = 0.f; }
  __syncthreads();

  const int j = t >> 3, g = t & 7;
  const float cmt = cm[j] * 6.f;
  const float gl = gleak[j];
  const float glv = gl * vleak[j];
  float psum = 0.f;
  const float* pn = wnum + b * 2304 + j;
  const float* pd = wden + b * 2304 + j;

  for (int s = 0; s < 48; ++s) {
    float wns = pn[s * 48], wds = pd[s * 48];
#pragma unroll 1
    for (int u = 0; u < 6; ++u) {
      int cur = u & 1;
      float an = 0.f, ad = 0.f;
#pragma unroll
      for (int q = 0; q < 6; ++q) {
        int i = g * 6 + q;
        float vi = vbuf[cur][i];
        float sg = sigmoid_f((vi - smu[i * 49 + j]) * ssg[i * 49 + j]);
        an += swe[i * 49 + j] * sg;
        ad += swm[i * 49 + j] * sg;
      }
      an += __shfl_xor(an, 1); ad += __shfl_xor(ad, 1);
      an += __shfl_xor(an, 2); ad += __shfl_xor(ad, 2);
      an += __shfl_xor(an, 4); ad += __shfl_xor(ad, 4);
      if (g == 0) {
        float vj = vbuf[cur][j];
        float num = cmt * vj + glv + an + wns;
        float den = cmt + gl + ad + wds + 1e-8f;
        vbuf[cur ^ 1][j] = num / den;
      }
      __syncthreads();
    }
    if (g == 0 && j < 4) psum += vbuf[0][j];
  }
  if (g == 0 && j < 4) m4[j] = psum * (1.f / 48.f) * w_out[j] + b_out[j];
  __syncthreads();
  if (t < 2) {
    float a = b_head[t];
#pragma unroll
    for (int jm = 0; jm < 4; ++jm) a += m4[jm] * w_head[jm * 2 + t];
    out[b * 2 + t] = tanhf(a);
  }
}

extern "C" void kernel_launch(void* const* d_in, const int* in_sizes, int n_in,
                              void* d_out, int out_size, void* d_ws, size_t ws_size,
                              hipStream_t stream) {
  const float* image   = (const float*)d_in[0];
  const float* rel     = (const float*)d_in[1];
  const float* w0      = (const float*)d_in[2];
  const float* b0      = (const float*)d_in[3];
  const float* w1      = (const float*)d_in[4];
  const float* b1      = (const float*)d_in[5];
  const float* w2      = (const float*)d_in[6];
  const float* b2      = (const float*)d_in[7];
  const float* iw      = (const float*)d_in[8];
  const float* ib      = (const float*)d_in[9];
  const float* gleak   = (const float*)d_in[10];
  const float* vleak   = (const float*)d_in[11];
  const float* cm      = (const float*)d_in[12];
  const float* sigma   = (const float*)d_in[13];
  const float* mu      = (const float*)d_in[14];
  const float* w_syn   = (const float*)d_in[15];
  const float* erev    = (const float*)d_in[16];
  const float* s_sigma = (const float*)d_in[17];
  const float* s_mu    = (const float*)d_in[18];
  const float* s_w     = (const float*)d_in[19];
  const float* s_erev  = (const float*)d_in[20];
  const float* w_out   = (const float*)d_in[21];
  const float* b_out   = (const float*)d_in[22];
  const float* w_head  = (const float*)d_in[23];
  const float* b_head  = (const float*)d_in[24];
  const int* syn_mask  = (const int*)d_in[25];
  const int* sens_mask = (const int*)d_in[26];
  float* ws  = (float*)d_ws;
  float* out = (float*)d_out;

  k_pre_sensory<<<(1283 * 48 + 255) / 256, 256, 0, stream>>>(
      s_sigma, s_mu, s_w, s_erev, sens_mask,
      ws + O_SSIG, ws + O_SMU, ws + O_SW, ws + O_SWE);
  k_pre_rec<<<9, 256, 0, stream>>>(w_syn, erev, syn_mask, ws + O_WM, ws + O_WME);
  k_pre_w<<<144, 256, 0, stream>>>(w1, w2, ws + O_W1T, ws + O_W2T);

  k_conv12<<<1536, 256, 0, stream>>>(image, w0, b0, ws + O_W1T, b1, ws + O_OUT2);
  k_conv3<<<1536, 256, 0, stream>>>(ws + O_OUT2, ws + O_W2T, b2, rel, ws + O_X);

  k_sensory<<<192, 256, 0, stream>>>(ws + O_X, iw, ib,
      ws + O_SSIG, ws + O_SMU, ws + O_SW, ws + O_SWE, ws + O_WNUM, ws + O_WDEN);

  k_scan<<<32, 384, 0, stream>>>(mu, sigma, ws + O_WM, ws + O_WME,
      ws + O_WNUM, ws + O_WDEN, gleak, vleak, cm,
      w_out, b_out, w_head, b_head, out);
}

// Round 3
// 1374.616 us; speedup vs baseline: 2.7987x; 2.7987x over previous
//
#include <hip/hip_runtime.h>
#include <math.h>

#define DINL __device__ __forceinline__

// ---------------- geometry ----------------
// image: [1536][48][72]
// conv1: -> [32][23][35]  (805 spatial)
// conv2: -> [64][11][17]  (187 spatial), stored as [n][sp][oc]
// conv3: -> [32][5][8]    (40 spatial) -> feat 1280, + rel_pos 3 -> 1283
// LTC: UNITS=48, ODE_UNFOLDS=6, S=48, B=32

static constexpr int O_OUT2 = 0;                         // [1536][187][64]
static constexpr int O_X    = O_OUT2 + 1536 * 187 * 64;  // [1536][1283]
static constexpr int O_WNUM = O_X + 1536 * 1283;         // [1536][48]
static constexpr int O_WDEN = O_WNUM + 1536 * 48;
static constexpr int O_SSIG = O_WDEN + 1536 * 48;        // [48][1283] transposed
static constexpr int O_SMU  = O_SSIG + 48 * 1283;
static constexpr int O_SW   = O_SMU + 48 * 1283;
static constexpr int O_SWE  = O_SW + 48 * 1283;
static constexpr int O_WM   = O_SWE + 48 * 1283;         // [48][48] w_syn*mask
static constexpr int O_WME  = O_WM + 48 * 48;            // [48][48] w_syn*mask*erev
static constexpr int O_W1T  = O_WME + 48 * 48;           // [32][9][64]: [c][k][oc]
static constexpr int O_W2T  = O_W1T + 32 * 9 * 64;       // [32][9][64]: [oc][k][c]

DINL float sigmoid_f(float z) {
  return __builtin_amdgcn_rcpf(1.f + __expf(-z));
}

// -------- pre: transpose sensory params to [j][i], fold mask & erev --------
__global__ void k_pre_sensory(const float* ssig, const float* smu, const float* sw,
                              const float* serev, const int* smask,
                              float* o_sig, float* o_mu, float* o_w, float* o_we) {
  int idx = blockIdx.x * 256 + threadIdx.x;
  if (idx >= 1283 * 48) return;
  int i = idx / 48, j = idx - i * 48;
  float m  = (float)smask[idx];
  float w  = sw[idx] * m;
  int o = j * 1283 + i;
  o_sig[o] = ssig[idx];
  o_mu[o]  = smu[idx];
  o_w[o]   = w;
  o_we[o]  = w * serev[idx];
}

// -------- pre: recurrent params, fold mask & erev (keep [i][j]) --------
__global__ void k_pre_rec(const float* w_syn, const float* erev, const int* mask,
                          float* o_wm, float* o_wme) {
  int idx = blockIdx.x * 256 + threadIdx.x;
  if (idx >= 48 * 48) return;
  float wm = w_syn[idx] * (float)mask[idx];
  o_wm[idx]  = wm;
  o_wme[idx] = wm * erev[idx];
}

// -------- pre: weight transposes for coalesced loads --------
__global__ void k_pre_w(const float* w1, const float* w2, float* w1t, float* w2t) {
  int idx = blockIdx.x * 256 + threadIdx.x;
  if (idx < 18432) {          // w1 [64][32][9] -> [c][k][oc]
    int oc = idx / 288;
    int rem = idx - oc * 288;
    int c = rem / 9, k = rem - c * 9;
    w1t[(c * 9 + k) * 64 + oc] = w1[idx];
  } else if (idx < 36864) {   // w2 [32][64][9] -> [oc][k][c]
    int i2 = idx - 18432;
    int oc = i2 / 576;
    int rem = i2 - oc * 576;
    int c = rem / 9, k = rem - c * 9;
    w2t[oc * 576 + k * 64 + c] = w2[i2];
  }
}

// -------- fused conv1 + conv2, one block per image, channel-sliced --------
// LDS: simg 3456 + sw0 288 + sb0 32 + sc1g 4*828 + sw1g 4*9*64 = 9392 fl
//      = 37.6 KB -> 4 blocks/CU.
// Register budget for (256,4) = 128 unified VGPR+AGPR. Live set kept ~90:
// acc[12][4]=48, wr[4][3]=12 (kh-tiled, NOT wr[4][9]=36), rowb[12], temps.
__global__ __launch_bounds__(256, 4) void k_conv12(const float* __restrict__ gimg,
        const float* __restrict__ w0, const float* __restrict__ b0,
        const float* __restrict__ w1t, const float* __restrict__ b1,
        float* __restrict__ gout2) {
  __shared__ float simg[3456];
  __shared__ float sw0[288];
  __shared__ float sb0[32];
  __shared__ float sc1g[4 * 828];   // 4 channels x [23][36] (36: 8B-aligned rows)
  __shared__ float sw1g[4 * 9 * 64];
  const int n = blockIdx.x, t = threadIdx.x;

  const float* gi = gimg + n * 3456;
  for (int k = t; k < 3456; k += 256) simg[k] = gi[k];
  for (int k = t; k < 288; k += 256) sw0[k] = w0[k];
  if (t < 32) sb0[t] = b0[t];

  // conv2 accumulators: thread = (ocq, g); oc in {ocq+16m}, sp = q*16+g
  const int ocq = t & 15, g = t >> 4;
  float acc[12][4];
  int rowb[12];
#pragma unroll
  for (int m = 0; m < 4; ++m) {
    float bb = b1[ocq + 16 * m];
#pragma unroll
    for (int q = 0; q < 12; ++q) acc[q][m] = bb;
  }
#pragma unroll
  for (int q = 0; q < 12; ++q) {
    int sp = q * 16 + g; if (sp > 186) sp = 186;
    int oh = sp / 17, ow = sp - oh * 17;
    rowb[q] = (2 * oh) * 36 + 2 * ow;
  }
  __syncthreads();

  for (int grp = 0; grp < 8; ++grp) {
    // stage w1 slice [4c][9k][64oc]
    for (int k = t; k < 2304; k += 256) sw1g[k] = w1t[grp * 2304 + k];
    // conv1 for channels 4*grp .. 4*grp+3
    for (int idx = t; idx < 3220; idx += 256) {
      int c4 = idx / 805, sp = idx - c4 * 805;
      int oh = sp / 35, ow = sp - oh * 35;
      const float* ip = simg + (2 * oh) * 72 + 2 * ow;
      const float* wp = sw0 + (grp * 4 + c4) * 9;
      float a = sb0[grp * 4 + c4];
#pragma unroll
      for (int kh = 0; kh < 3; ++kh)
        a += ip[kh * 72 + 0] * wp[kh * 3 + 0] + ip[kh * 72 + 1] * wp[kh * 3 + 1]
           + ip[kh * 72 + 2] * wp[kh * 3 + 2];
      sc1g[c4 * 828 + oh * 36 + ow] = fmaxf(a, 0.f);
    }
    __syncthreads();

#pragma unroll 1
    for (int c4 = 0; c4 < 4; ++c4) {
      const float* cb = sc1g + c4 * 828;
      const float* wb = sw1g + c4 * 576;
#pragma unroll
      for (int kh = 0; kh < 3; ++kh) {
        float wr[4][3];
#pragma unroll
        for (int kw = 0; kw < 3; ++kw)
#pragma unroll
          for (int m = 0; m < 4; ++m)
            wr[m][kw] = wb[(kh * 3 + kw) * 64 + ocq + 16 * m];
#pragma unroll
        for (int q = 0; q < 12; ++q) {
          const float* p = cb + rowb[q] + kh * 36;
          float x0 = p[0], x1 = p[1], x2 = p[2];
#pragma unroll
          for (int m = 0; m < 4; ++m)
            acc[q][m] += x0 * wr[m][0] + x1 * wr[m][1] + x2 * wr[m][2];
        }
      }
    }
    __syncthreads();
  }

  float* go = gout2 + n * 11968;
#pragma unroll
  for (int q = 0; q < 12; ++q) {
    int sp = q * 16 + g;
    if (sp < 187)
#pragma unroll
      for (int m = 0; m < 4; ++m)
        go[sp * 64 + ocq + 16 * m] = fmaxf(acc[q][m], 0.f);
  }
}

// -------- conv3 + concat, one block per image, channel-sliced --------
// LDS: sin2g [187][17]=3179 + sw2g [32][145]=4640 + 32 = 31.4 KB -> 5 blk/CU
__global__ __launch_bounds__(256, 5) void k_conv3(const float* __restrict__ gout2,
        const float* __restrict__ w2t, const float* __restrict__ b2,
        const float* __restrict__ grel, float* __restrict__ gx) {
  __shared__ float sin2g[187 * 17];   // [sp_in][c16], row pad 17
  __shared__ float sw2g[32 * 145];    // [oc][9k*16c], oc stride 145
  const int n = blockIdx.x, t = threadIdx.x;
  const float* gi = gout2 + n * 11968;

  const int oc = t & 15, g = t >> 4;   // oc handles {oc, oc+16}; sp = q*16+g
  float acc[3][2];
  int rowb[3];
#pragma unroll
  for (int q = 0; q < 3; ++q) {
    acc[q][0] = b2[oc]; acc[q][1] = b2[oc + 16];
    int sp = q * 16 + g; if (sp > 39) sp = 39;
    int oh = sp >> 3, ow = sp & 7;
    rowb[q] = ((2 * oh) * 17 + 2 * ow) * 17;   // input spatial base * row-pad
  }

  for (int grp = 0; grp < 4; ++grp) {
    // stage input channel slice [187 sp][16 c]
    for (int idx = t; idx < 2992; idx += 256) {
      int sp = idx >> 4, c = idx & 15;
      sin2g[sp * 17 + c] = gi[sp * 64 + grp * 16 + c];
    }
    // stage weight slice [32 oc][9k x 16c]
    for (int idx = t; idx < 4608; idx += 256) {
      int oc2 = idx / 144, r = idx - oc2 * 144;  // r = k*16 + c
      sw2g[oc2 * 145 + r] = w2t[oc2 * 576 + (r >> 4) * 64 + grp * 16 + (r & 15)];
    }
    __syncthreads();

    for (int c = 0; c < 16; ++c) {
      float wr0[9], wr1[9];
#pragma unroll
      for (int k = 0; k < 9; ++k) {
        wr0[k] = sw2g[oc * 145 + k * 16 + c];
        wr1[k] = sw2g[(oc + 16) * 145 + k * 16 + c];
      }
#pragma unroll
      for (int q = 0; q < 3; ++q) {
        const float* p = sin2g + rowb[q] + c;
#pragma unroll
        for (int kh = 0; kh < 3; ++kh) {
          float x0 = p[kh * 289], x1 = p[kh * 289 + 17], x2 = p[kh * 289 + 34];
          acc[q][0] += x0 * wr0[3 * kh] + x1 * wr0[3 * kh + 1] + x2 * wr0[3 * kh + 2];
          acc[q][1] += x0 * wr1[3 * kh] + x1 * wr1[3 * kh + 1] + x2 * wr1[3 * kh + 2];
        }
      }
    }
    __syncthreads();
  }

  float* xo = gx + n * 1283;
#pragma unroll
  for (int q = 0; q < 3; ++q) {
    int sp = q * 16 + g;
    if (sp < 40) {
      xo[oc * 40 + sp]        = fmaxf(acc[q][0], 0.f);
      xo[(oc + 16) * 40 + sp] = fmaxf(acc[q][1], 0.f);
    }
  }
  if (t < 3) xo[1280 + t] = grel[n * 3 + t];
}

// -------- sensory synapse sums: 8 time-slots per block --------
__global__ __launch_bounds__(256) void k_sensory(const float* __restrict__ gx,
        const float* __restrict__ iw, const float* __restrict__ ib,
        const float* __restrict__ psig, const float* __restrict__ pmu,
        const float* __restrict__ pw, const float* __restrict__ pwe,
        float* __restrict__ wnum, float* __restrict__ wden) {
  __shared__ float xs[8 * 1283];
  const int t = threadIdx.x;
  const int bs0 = blockIdx.x * 8;
  for (int idx = t; idx < 8 * 1283; idx += 256) {
    int slot = idx / 1283, i = idx - slot * 1283;
    xs[idx] = gx[(bs0 + slot) * 1283 + i] * iw[i] + ib[i];
  }
  __syncthreads();
  const int w = t >> 6, l = t & 63;
  for (int jj = 0; jj < 12; ++jj) {
    int j = w * 12 + jj;
    const float* pa = psig + j * 1283;
    const float* pm = pmu + j * 1283;
    const float* pww = pw + j * 1283;
    const float* pe = pwe + j * 1283;
    float an[8], ad[8];
#pragma unroll
    for (int s2 = 0; s2 < 8; ++s2) { an[s2] = 0.f; ad[s2] = 0.f; }
    for (int i = l; i < 1283; i += 64) {
      float a = pa[i], m = pm[i], ww = pww[i], we = pe[i];
#pragma unroll
      for (int s2 = 0; s2 < 8; ++s2) {
        float sg = sigmoid_f((xs[s2 * 1283 + i] - m) * a);
        an[s2] += we * sg;
        ad[s2] += ww * sg;
      }
    }
#pragma unroll
    for (int off = 32; off; off >>= 1)
#pragma unroll
      for (int s2 = 0; s2 < 8; ++s2) {
        an[s2] += __shfl_xor(an[s2], off);
        ad[s2] += __shfl_xor(ad[s2], off);
      }
    if (l == 0) {
#pragma unroll
      for (int s2 = 0; s2 < 8; ++s2) {
        wnum[(bs0 + s2) * 48 + j] = an[s2];
        wden[(bs0 + s2) * 48 + j] = ad[s2];
      }
    }
  }
}

// -------- LTC scan: one block per batch, 48 posts x 8 pre-groups --------
__global__ __launch_bounds__(384) void k_scan(const float* __restrict__ gmu,
        const float* __restrict__ gsig, const float* __restrict__ wm,
        const float* __restrict__ wme, const float* __restrict__ wnum,
        const float* __restrict__ wden, const float* __restrict__ gleak,
        const float* __restrict__ vleak, const float* __restrict__ cm,
        const float* __restrict__ w_out, const float* __restrict__ b_out,
        const float* __restrict__ w_head, const float* __restrict__ b_head,
        float* __restrict__ out) {
  __shared__ float smu[48 * 49], ssg[48 * 49], swm[48 * 49], swe[48 * 49];
  __shared__ float vbuf[2][48];
  __shared__ float m4[4];
  const int t = threadIdx.x, b = blockIdx.x;
  for (int idx = t; idx < 2304; idx += 384) {
    int i = idx / 48, jx = idx - i * 48;
    int o = i * 49 + jx;
    smu[o] = gmu[idx]; ssg[o] = gsig[idx];
    swm[o] = wm[idx];  swe[o] = wme[idx];
  }
  if (t < 48) { vbuf[0][t] = 0.f; vbuf[1][t] = 0.f; }
  __syncthreads();

  const int j = t >> 3, g = t & 7;
  const float cmt = cm[j] * 6.f;
  const float gl = gleak[j];
  const float glv = gl * vleak[j];
  float psum = 0.f;
  const float* pn = wnum + b * 2304 + j;
  const float* pd = wden + b * 2304 + j;

  for (int s = 0; s < 48; ++s) {
    float wns = pn[s * 48], wds = pd[s * 48];
#pragma unroll 1
    for (int u = 0; u < 6; ++u) {
      int cur = u & 1;
      float an = 0.f, ad = 0.f;
#pragma unroll
      for (int q = 0; q < 6; ++q) {
        int i = g * 6 + q;
        float vi = vbuf[cur][i];
        float sg = sigmoid_f((vi - smu[i * 49 + j]) * ssg[i * 49 + j]);
        an += swe[i * 49 + j] * sg;
        ad += swm[i * 49 + j] * sg;
      }
      an += __shfl_xor(an, 1); ad += __shfl_xor(ad, 1);
      an += __shfl_xor(an, 2); ad += __shfl_xor(ad, 2);
      an += __shfl_xor(an, 4); ad += __shfl_xor(ad, 4);
      if (g == 0) {
        float vj = vbuf[cur][j];
        float num = cmt * vj + glv + an + wns;
        float den = cmt + gl + ad + wds + 1e-8f;
        vbuf[cur ^ 1][j] = num / den;
      }
      __syncthreads();
    }
    if (g == 0 && j < 4) psum += vbuf[0][j];
  }
  if (g == 0 && j < 4) m4[j] = psum * (1.f / 48.f) * w_out[j] + b_out[j];
  __syncthreads();
  if (t < 2) {
    float a = b_head[t];
#pragma unroll
    for (int jm = 0; jm < 4; ++jm) a += m4[jm] * w_head[jm * 2 + t];
    out[b * 2 + t] = tanhf(a);
  }
}

extern "C" void kernel_launch(void* const* d_in, const int* in_sizes, int n_in,
                              void* d_out, int out_size, void* d_ws, size_t ws_size,
                              hipStream_t stream) {
  const float* image   = (const float*)d_in[0];
  const float* rel     = (const float*)d_in[1];
  const float* w0      = (const float*)d_in[2];
  const float* b0      = (const float*)d_in[3];
  const float* w1      = (const float*)d_in[4];
  const float* b1      = (const float*)d_in[5];
  const float* w2      = (const float*)d_in[6];
  const float* b2      = (const float*)d_in[7];
  const float* iw      = (const float*)d_in[8];
  const float* ib      = (const float*)d_in[9];
  const float* gleak   = (const float*)d_in[10];
  const float* vleak   = (const float*)d_in[11];
  const float* cm      = (const float*)d_in[12];
  const float* sigma   = (const float*)d_in[13];
  const float* mu      = (const float*)d_in[14];
  const float* w_syn   = (const float*)d_in[15];
  const float* erev    = (const float*)d_in[16];
  const float* s_sigma = (const float*)d_in[17];
  const float* s_mu    = (const float*)d_in[18];
  const float* s_w     = (const float*)d_in[19];
  const float* s_erev  = (const float*)d_in[20];
  const float* w_out   = (const float*)d_in[21];
  const float* b_out   = (const float*)d_in[22];
  const float* w_head  = (const float*)d_in[23];
  const float* b_head  = (const float*)d_in[24];
  const int* syn_mask  = (const int*)d_in[25];
  const int* sens_mask = (const int*)d_in[26];
  float* ws  = (float*)d_ws;
  float* out = (float*)d_out;

  k_pre_sensory<<<(1283 * 48 + 255) / 256, 256, 0, stream>>>(
      s_sigma, s_mu, s_w, s_erev, sens_mask,
      ws + O_SSIG, ws + O_SMU, ws + O_SW, ws + O_SWE);
  k_pre_rec<<<9, 256, 0, stream>>>(w_syn, erev, syn_mask, ws + O_WM, ws + O_WME);
  k_pre_w<<<144, 256, 0, stream>>>(w1, w2, ws + O_W1T, ws + O_W2T);

  k_conv12<<<1536, 256, 0, stream>>>(image, w0, b0, ws + O_W1T, b1, ws + O_OUT2);
  k_conv3<<<1536, 256, 0, stream>>>(ws + O_OUT2, ws + O_W2T, b2, rel, ws + O_X);

  k_sensory<<<192, 256, 0, stream>>>(ws + O_X, iw, ib,
      ws + O_SSIG, ws + O_SMU, ws + O_SW, ws + O_SWE, ws + O_WNUM, ws + O_WDEN);

  k_scan<<<32, 384, 0, stream>>>(mu, sigma, ws + O_WM, ws + O_WME,
      ws + O_WNUM, ws + O_WDEN, gleak, vleak, cm,
      w_out, b_out, w_head, b_head, out);
}

// Round 5
// 762.196 us; speedup vs baseline: 5.0475x; 1.8035x over previous
//
#include <hip/hip_runtime.h>
#include <math.h>

#define DINL __device__ __forceinline__

// ---------------- geometry ----------------
// image: [1536][48][72]
// conv1: -> [32][23][35]  (805 spatial)
// conv2: -> [64][11][17]  (187 spatial), stored as [n][sp][oc]
// conv3: -> [32][5][8]    (40 spatial) -> feat 1280, + rel_pos 3 -> 1283
// LTC: UNITS=48, ODE_UNFOLDS=6, S=48, B=32

static constexpr int O_OUT2 = 0;                         // [1536][187][64]
static constexpr int O_X    = O_OUT2 + 1536 * 187 * 64;  // [1536][1283]
static constexpr int O_WNUM = O_X + 1536 * 1283;         // [1536][48]
static constexpr int O_WDEN = O_WNUM + 1536 * 48;
static constexpr int O_SSIG = O_WDEN + 1536 * 48;        // [48][1283] transposed
static constexpr int O_SMU  = O_SSIG + 48 * 1283;
static constexpr int O_SW   = O_SMU + 48 * 1283;
static constexpr int O_SWE  = O_SW + 48 * 1283;
static constexpr int O_WM   = O_SWE + 48 * 1283;         // [48][48] w_syn*mask
static constexpr int O_WME  = O_WM + 48 * 48;            // [48][48] w_syn*mask*erev
static constexpr int O_W1T  = O_WME + 48 * 48;           // [32][9][64]: [c][k][oc]
static constexpr int O_W2T  = O_W1T + 32 * 9 * 64;       // [32][9][64]: [oc][k][c]

DINL float sigmoid_f(float z) {
  return __builtin_amdgcn_rcpf(1.f + __expf(-z));
}

// -------- pre: transpose sensory params to [j][i], fold mask & erev --------
__global__ void k_pre_sensory(const float* ssig, const float* smu, const float* sw,
                              const float* serev, const int* smask,
                              float* o_sig, float* o_mu, float* o_w, float* o_we) {
  int idx = blockIdx.x * 256 + threadIdx.x;
  if (idx >= 1283 * 48) return;
  int i = idx / 48, j = idx - i * 48;
  float m  = (float)smask[idx];
  float w  = sw[idx] * m;
  int o = j * 1283 + i;
  o_sig[o] = ssig[idx];
  o_mu[o]  = smu[idx];
  o_w[o]   = w;
  o_we[o]  = w * serev[idx];
}

// -------- pre: recurrent params, fold mask & erev (keep [i][j]) --------
__global__ void k_pre_rec(const float* w_syn, const float* erev, const int* mask,
                          float* o_wm, float* o_wme) {
  int idx = blockIdx.x * 256 + threadIdx.x;
  if (idx >= 48 * 48) return;
  float wm = w_syn[idx] * (float)mask[idx];
  o_wm[idx]  = wm;
  o_wme[idx] = wm * erev[idx];
}

// -------- pre: weight transposes for coalesced loads --------
__global__ void k_pre_w(const float* w1, const float* w2, float* w1t, float* w2t) {
  int idx = blockIdx.x * 256 + threadIdx.x;
  if (idx < 18432) {          // w1 [64][32][9] -> [c][k][oc]
    int oc = idx / 288;
    int rem = idx - oc * 288;
    int c = rem / 9, k = rem - c * 9;
    w1t[(c * 9 + k) * 64 + oc] = w1[idx];
  } else if (idx < 36864) {   // w2 [32][64][9] -> [oc][k][c]
    int i2 = idx - 18432;
    int oc = i2 / 576;
    int rem = i2 - oc * 576;
    int c = rem / 9, k = rem - c * 9;
    w2t[oc * 576 + k * 64 + c] = w2[i2];
  }
}

// -------- fused conv1 + conv2, one block per image, channel-sliced --------
// 512 threads. LDS 37.6 KB. __launch_bounds__(512,4) -> 2 blocks/CU
// (16 waves/CU), 128 unified regs/wave. Live set ~60:
// acc[6][4]=24, wr[4][3]=12, rowb[6]=6, temps — fits, NO spill (the
// Round-2/3 failure was acc[12][4]=48 blowing the 128 budget).
__global__ __launch_bounds__(512, 4) void k_conv12(const float* __restrict__ gimg,
        const float* __restrict__ w0, const float* __restrict__ b0,
        const float* __restrict__ w1t, const float* __restrict__ b1,
        float* __restrict__ gout2) {
  __shared__ float simg[3456];
  __shared__ float sw0[288];
  __shared__ float sb0[32];
  __shared__ float sc1g[4 * 828];   // 4 channels x [23][36] (36: 8B-aligned rows)
  __shared__ float sw1g[4 * 9 * 64];
  const int n = blockIdx.x, t = threadIdx.x;

  const float* gi = gimg + n * 3456;
  for (int k = t; k < 3456; k += 512) simg[k] = gi[k];
  if (t < 288) sw0[t] = w0[t];
  if (t >= 480) sb0[t - 480] = b0[t - 480];

  // conv2 accumulators: thread = (ocq, g); oc in {ocq+16m}, sp = q*32+g
  const int ocq = t & 15, g = t >> 4;   // g in 0..31
  float acc[6][4];
  int rowb[6];
#pragma unroll
  for (int m = 0; m < 4; ++m) {
    float bb = b1[ocq + 16 * m];
#pragma unroll
    for (int q = 0; q < 6; ++q) acc[q][m] = bb;
  }
#pragma unroll
  for (int q = 0; q < 6; ++q) {
    int sp = q * 32 + g; if (sp > 186) sp = 186;
    int oh = sp / 17, ow = sp - oh * 17;
    rowb[q] = (2 * oh) * 36 + 2 * ow;
  }
  __syncthreads();

  for (int grp = 0; grp < 8; ++grp) {
    // stage w1 slice [4c][9k][64oc]
    for (int k = t; k < 2304; k += 512) sw1g[k] = w1t[grp * 2304 + k];
    // conv1 for channels 4*grp .. 4*grp+3
    for (int idx = t; idx < 3220; idx += 512) {
      int c4 = idx / 805, sp = idx - c4 * 805;
      int oh = sp / 35, ow = sp - oh * 35;
      const float* ip = simg + (2 * oh) * 72 + 2 * ow;
      const float* wp = sw0 + (grp * 4 + c4) * 9;
      float a = sb0[grp * 4 + c4];
#pragma unroll
      for (int kh = 0; kh < 3; ++kh)
        a += ip[kh * 72 + 0] * wp[kh * 3 + 0] + ip[kh * 72 + 1] * wp[kh * 3 + 1]
           + ip[kh * 72 + 2] * wp[kh * 3 + 2];
      sc1g[c4 * 828 + oh * 36 + ow] = fmaxf(a, 0.f);
    }
    __syncthreads();

#pragma unroll 1
    for (int c4 = 0; c4 < 4; ++c4) {
      const float* cb = sc1g + c4 * 828;
      const float* wb = sw1g + c4 * 576;
#pragma unroll
      for (int kh = 0; kh < 3; ++kh) {
        float wr[4][3];
#pragma unroll
        for (int kw = 0; kw < 3; ++kw)
#pragma unroll
          for (int m = 0; m < 4; ++m)
            wr[m][kw] = wb[(kh * 3 + kw) * 64 + ocq + 16 * m];
#pragma unroll
        for (int q = 0; q < 6; ++q) {
          const float* p = cb + rowb[q] + kh * 36;
          float x0 = p[0], x1 = p[1], x2 = p[2];
#pragma unroll
          for (int m = 0; m < 4; ++m)
            acc[q][m] += x0 * wr[m][0] + x1 * wr[m][1] + x2 * wr[m][2];
        }
      }
    }
    __syncthreads();
  }

  float* go = gout2 + n * 11968;
#pragma unroll
  for (int q = 0; q < 6; ++q) {
    int sp = q * 32 + g;
    if (sp < 187)
#pragma unroll
      for (int m = 0; m < 4; ++m)
        go[sp * 64 + ocq + 16 * m] = fmaxf(acc[q][m], 0.f);
  }
}

// -------- conv3 + concat, one block per image, channel-sliced --------
// LDS: sin2g [187][17]=3179 + sw2g [32][145]=4640 = 31.4 KB. (256,4).
// Index map for sin2g: sp = h*17 + w, each sp at stride 17 (pad).
// One input ROW down = +17 sp = +289 floats (Round-4 bug: had 578 = 2 rows,
// which also read past sin2g's end. Bounds: rowb<=2550, +2*289+34+15=3177<3179.)
__global__ __launch_bounds__(256, 4) void k_conv3(const float* __restrict__ gout2,
        const float* __restrict__ w2t, const float* __restrict__ b2,
        const float* __restrict__ grel, float* __restrict__ gx) {
  __shared__ float sin2g[187 * 17];   // [sp_in][c16], row pad 17
  __shared__ float sw2g[32 * 145];    // [oc][9k*16c], oc stride 145
  const int n = blockIdx.x, t = threadIdx.x;
  const float* gi = gout2 + n * 11968;

  const int oc = t & 15, g = t >> 4;   // oc handles {oc, oc+16}; sp = q*16+g
  float acc[3][2];
  int rowb[3];
#pragma unroll
  for (int q = 0; q < 3; ++q) {
    acc[q][0] = b2[oc]; acc[q][1] = b2[oc + 16];
    int sp = q * 16 + g; if (sp > 39) sp = 39;
    int oh = sp >> 3, ow = sp & 7;
    rowb[q] = ((2 * oh) * 17 + 2 * ow) * 17;   // input spatial base * row-pad
  }

  for (int grp = 0; grp < 4; ++grp) {
    // stage input channel slice [187 sp][16 c]
    for (int idx = t; idx < 2992; idx += 256) {
      int sp = idx >> 4, c = idx & 15;
      sin2g[sp * 17 + c] = gi[sp * 64 + grp * 16 + c];
    }
    // stage weight slice [32 oc][9k x 16c]
    for (int idx = t; idx < 4608; idx += 256) {
      int oc2 = idx / 144, r = idx - oc2 * 144;  // r = k*16 + c
      sw2g[oc2 * 145 + r] = w2t[oc2 * 576 + (r >> 4) * 64 + grp * 16 + (r & 15)];
    }
    __syncthreads();

    for (int c = 0; c < 16; ++c) {
#pragma unroll
      for (int kh = 0; kh < 3; ++kh) {
        float wr0[3], wr1[3];
#pragma unroll
        for (int kw = 0; kw < 3; ++kw) {
          wr0[kw] = sw2g[oc * 145 + (kh * 3 + kw) * 16 + c];
          wr1[kw] = sw2g[(oc + 16) * 145 + (kh * 3 + kw) * 16 + c];
        }
#pragma unroll
        for (int q = 0; q < 3; ++q) {
          const float* p = sin2g + rowb[q] + kh * 289 + c;
          float x0 = p[0], x1 = p[17], x2 = p[34];
          acc[q][0] += x0 * wr0[0] + x1 * wr0[1] + x2 * wr0[2];
          acc[q][1] += x0 * wr1[0] + x1 * wr1[1] + x2 * wr1[2];
        }
      }
    }
    __syncthreads();
  }

  float* xo = gx + n * 1283;
#pragma unroll
  for (int q = 0; q < 3; ++q) {
    int sp = q * 16 + g;
    if (sp < 40) {
      xo[oc * 40 + sp]        = fmaxf(acc[q][0], 0.f);
      xo[(oc + 16) * 40 + sp] = fmaxf(acc[q][1], 0.f);
    }
  }
  if (t < 3) xo[1280 + t] = grel[n * 3 + t];
}

// -------- sensory synapse sums: 8 time-slots per block --------
__global__ __launch_bounds__(256) void k_sensory(const float* __restrict__ gx,
        const float* __restrict__ iw, const float* __restrict__ ib,
        const float* __restrict__ psig, const float* __restrict__ pmu,
        const float* __restrict__ pw, const float* __restrict__ pwe,
        float* __restrict__ wnum, float* __restrict__ wden) {
  __shared__ float xs[8 * 1283];
  const int t = threadIdx.x;
  const int bs0 = blockIdx.x * 8;
  for (int idx = t; idx < 8 * 1283; idx += 256) {
    int slot = idx / 1283, i = idx - slot * 1283;
    xs[idx] = gx[(bs0 + slot) * 1283 + i] * iw[i] + ib[i];
  }
  __syncthreads();
  const int w = t >> 6, l = t & 63;
  for (int jj = 0; jj < 12; ++jj) {
    int j = w * 12 + jj;
    const float* pa = psig + j * 1283;
    const float* pm = pmu + j * 1283;
    const float* pww = pw + j * 1283;
    const float* pe = pwe + j * 1283;
    float an[8], ad[8];
#pragma unroll
    for (int s2 = 0; s2 < 8; ++s2) { an[s2] = 0.f; ad[s2] = 0.f; }
    for (int i = l; i < 1283; i += 64) {
      float a = pa[i], m = pm[i], ww = pww[i], we = pe[i];
#pragma unroll
      for (int s2 = 0; s2 < 8; ++s2) {
        float sg = sigmoid_f((xs[s2 * 1283 + i] - m) * a);
        an[s2] += we * sg;
        ad[s2] += ww * sg;
      }
    }
#pragma unroll
    for (int off = 32; off; off >>= 1)
#pragma unroll
      for (int s2 = 0; s2 < 8; ++s2) {
        an[s2] += __shfl_xor(an[s2], off);
        ad[s2] += __shfl_xor(ad[s2], off);
      }
    if (l == 0) {
#pragma unroll
      for (int s2 = 0; s2 < 8; ++s2) {
        wnum[(bs0 + s2) * 48 + j] = an[s2];
        wden[(bs0 + s2) * 48 + j] = ad[s2];
      }
    }
  }
}

// -------- LTC scan: one block per batch, 48 posts x 8 pre-groups --------
__global__ __launch_bounds__(384) void k_scan(const float* __restrict__ gmu,
        const float* __restrict__ gsig, const float* __restrict__ wm,
        const float* __restrict__ wme, const float* __restrict__ wnum,
        const float* __restrict__ wden, const float* __restrict__ gleak,
        const float* __restrict__ vleak, const float* __restrict__ cm,
        const float* __restrict__ w_out, const float* __restrict__ b_out,
        const float* __restrict__ w_head, const float* __restrict__ b_head,
        float* __restrict__ out) {
  __shared__ float smu[48 * 49], ssg[48 * 49], swm[48 * 49], swe[48 * 49];
  __shared__ float vbuf[2][48];
  __shared__ float m4[4];
  const int t = threadIdx.x, b = blockIdx.x;
  for (int idx = t; idx < 2304; idx += 384) {
    int i = idx / 48, jx = idx - i * 48;
    int o = i * 49 + jx;
    smu[o] = gmu[idx]; ssg[o] = gsig[idx];
    swm[o] = wm[idx];  swe[o] = wme[idx];
  }
  if (t < 48) { vbuf[0][t] = 0.f; vbuf[1][t] = 0.f; }
  __syncthreads();

  const int j = t >> 3, g = t & 7;
  const float cmt = cm[j] * 6.f;
  const float gl = gleak[j];
  const float glv = gl * vleak[j];
  float psum = 0.f;
  const float* pn = wnum + b * 2304 + j;
  const float* pd = wden + b * 2304 + j;

  for (int s = 0; s < 48; ++s) {
    float wns = pn[s * 48], wds = pd[s * 48];
#pragma unroll 1
    for (int u = 0; u < 6; ++u) {
      int cur = u & 1;
      float an = 0.f, ad = 0.f;
#pragma unroll
      for (int q = 0; q < 6; ++q) {
        int i = g * 6 + q;
        float vi = vbuf[cur][i];
        float sg = sigmoid_f((vi - smu[i * 49 + j]) * ssg[i * 49 + j]);
        an += swe[i * 49 + j] * sg;
        ad += swm[i * 49 + j] * sg;
      }
      an += __shfl_xor(an, 1); ad += __shfl_xor(ad, 1);
      an += __shfl_xor(an, 2); ad += __shfl_xor(ad, 2);
      an += __shfl_xor(an, 4); ad += __shfl_xor(ad, 4);
      if (g == 0) {
        float vj = vbuf[cur][j];
        float num = cmt * vj + glv + an + wns;
        float den = cmt + gl + ad + wds + 1e-8f;
        vbuf[cur ^ 1][j] = num / den;
      }
      __syncthreads();
    }
    if (g == 0 && j < 4) psum += vbuf[0][j];
  }
  if (g == 0 && j < 4) m4[j] = psum * (1.f / 48.f) * w_out[j] + b_out[j];
  __syncthreads();
  if (t < 2) {
    float a = b_head[t];
#pragma unroll
    for (int jm = 0; jm < 4; ++jm) a += m4[jm] * w_head[jm * 2 + t];
    out[b * 2 + t] = tanhf(a);
  }
}

extern "C" void kernel_launch(void* const* d_in, const int* in_sizes, int n_in,
                              void* d_out, int out_size, void* d_ws, size_t ws_size,
                              hipStream_t stream) {
  const float* image   = (const float*)d_in[0];
  const float* rel     = (const float*)d_in[1];
  const float* w0      = (const float*)d_in[2];
  const float* b0      = (const float*)d_in[3];
  const float* w1      = (const float*)d_in[4];
  const float* b1      = (const float*)d_in[5];
  const float* w2      = (const float*)d_in[6];
  const float* b2      = (const float*)d_in[7];
  const float* iw      = (const float*)d_in[8];
  const float* ib      = (const float*)d_in[9];
  const float* gleak   = (const float*)d_in[10];
  const float* vleak   = (const float*)d_in[11];
  const float* cm      = (const float*)d_in[12];
  const float* sigma   = (const float*)d_in[13];
  const float* mu      = (const float*)d_in[14];
  const float* w_syn   = (const float*)d_in[15];
  const float* erev    = (const float*)d_in[16];
  const float* s_sigma = (const float*)d_in[17];
  const float* s_mu    = (const float*)d_in[18];
  const float* s_w     = (const float*)d_in[19];
  const float* s_erev  = (const float*)d_in[20];
  const float* w_out   = (const float*)d_in[21];
  const float* b_out   = (const float*)d_in[22];
  const float* w_head  = (const float*)d_in[23];
  const float* b_head  = (const float*)d_in[24];
  const int* syn_mask  = (const int*)d_in[25];
  const int* sens_mask = (const int*)d_in[26];
  float* ws  = (float*)d_ws;
  float* out = (float*)d_out;

  k_pre_sensory<<<(1283 * 48 + 255) / 256, 256, 0, stream>>>(
      s_sigma, s_mu, s_w, s_erev, sens_mask,
      ws + O_SSIG, ws + O_SMU, ws + O_SW, ws + O_SWE);
  k_pre_rec<<<9, 256, 0, stream>>>(w_syn, erev, syn_mask, ws + O_WM, ws + O_WME);
  k_pre_w<<<144, 256, 0, stream>>>(w1, w2, ws + O_W1T, ws + O_W2T);

  k_conv12<<<1536, 512, 0, stream>>>(image, w0, b0, ws + O_W1T, b1, ws + O_OUT2);
  k_conv3<<<1536, 256, 0, stream>>>(ws + O_OUT2, ws + O_W2T, b2, rel, ws + O_X);

  k_sensory<<<192, 256, 0, stream>>>(ws + O_X, iw, ib,
      ws + O_SSIG, ws + O_SMU, ws + O_SW, ws + O_SWE, ws + O_WNUM, ws + O_WDEN);

  k_scan<<<32, 384, 0, stream>>>(mu, sigma, ws + O_WM, ws + O_WME,
      ws + O_WNUM, ws + O_WDEN, gleak, vleak, cm,
      w_out, b_out, w_head, b_head, out);
}

// Round 6
// 751.231 us; speedup vs baseline: 5.1212x; 1.0146x over previous
//
#include <hip/hip_runtime.h>
#include <math.h>

#define DINL __device__ __forceinline__

// ---------------- geometry ----------------
// image: [1536][48][72]
// conv1: -> [32][23][35]  (805 spatial)
// conv2: -> [64][11][17]  (187 spatial), stored as [n][sp][oc]
// conv3: -> [32][5][8]    (40 spatial) -> feat 1280, + rel_pos 3 -> 1283
// LTC: UNITS=48, ODE_UNFOLDS=6, S=48, B=32

static constexpr int O_OUT2 = 0;                         // [1536][187][64]
static constexpr int O_X    = O_OUT2 + 1536 * 187 * 64;  // [1536][1283]
static constexpr int O_WNUM = O_X + 1536 * 1283;         // [1536][48]
static constexpr int O_WDEN = O_WNUM + 1536 * 48;
static constexpr int O_SSIG = O_WDEN + 1536 * 48;        // [48][1283] transposed
static constexpr int O_SMU  = O_SSIG + 48 * 1283;
static constexpr int O_SW   = O_SMU + 48 * 1283;
static constexpr int O_SWE  = O_SW + 48 * 1283;
static constexpr int O_WM   = O_SWE + 48 * 1283;         // [48][48] w_syn*mask
static constexpr int O_WME  = O_WM + 48 * 48;            // [48][48] w_syn*mask*erev
static constexpr int O_W1T  = O_WME + 48 * 48;           // [c][k][ocq][4m]
static constexpr int O_W2T  = O_W1T + 32 * 9 * 64;       // [ocq][k][c][2m]

DINL float sigmoid_f(float z) {
  return __builtin_amdgcn_rcpf(1.f + __expf(-z));
}

// -------- pre: transpose sensory params to [j][i], fold mask & erev --------
__global__ void k_pre_sensory(const float* ssig, const float* smu, const float* sw,
                              const float* serev, const int* smask,
                              float* o_sig, float* o_mu, float* o_w, float* o_we) {
  int idx = blockIdx.x * 256 + threadIdx.x;
  if (idx >= 1283 * 48) return;
  int i = idx / 48, j = idx - i * 48;
  float m  = (float)smask[idx];
  float w  = sw[idx] * m;
  int o = j * 1283 + i;
  o_sig[o] = ssig[idx];
  o_mu[o]  = smu[idx];
  o_w[o]   = w;
  o_we[o]  = w * serev[idx];
}

// -------- pre: recurrent params, fold mask & erev (keep [i][j]) --------
__global__ void k_pre_rec(const float* w_syn, const float* erev, const int* mask,
                          float* o_wm, float* o_wme) {
  int idx = blockIdx.x * 256 + threadIdx.x;
  if (idx >= 48 * 48) return;
  float wm = w_syn[idx] * (float)mask[idx];
  o_wm[idx]  = wm;
  o_wme[idx] = wm * erev[idx];
}

// -------- pre: weight repacks for vectorized LDS reads --------
// w1: [64oc][32c][9k] -> w1t[((c*9+k)*16 + ocq)*4 + m], oc = ocq + 16m.
//     Thread (ocq) reads its 4 oc-weights as ONE float4 (b128).
// w2: [32oc][64c][9k] -> w2t[((ocq*9+k)*64 + c)*2 + m], oc = ocq + 16m.
//     Thread reads its 2 oc-weights as ONE float2 (b64).
__global__ void k_pre_w(const float* w1, const float* w2, float* w1t, float* w2t) {
  int idx = blockIdx.x * 256 + threadIdx.x;
  if (idx < 18432) {
    int oc = idx / 288;
    int rem = idx - oc * 288;
    int c = rem / 9, k = rem - c * 9;
    w1t[((c * 9 + k) * 16 + (oc & 15)) * 4 + (oc >> 4)] = w1[idx];
  } else if (idx < 36864) {
    int i2 = idx - 18432;
    int oc = i2 / 576;
    int rem = i2 - oc * 576;
    int c = rem / 9, k = rem - c * 9;
    w2t[(((oc & 15) * 9 + k) * 64 + c) * 2 + (oc >> 4)] = w2[i2];
  }
}

// -------- fused conv1 + conv2, one block per image, channel-sliced --------
// 512 threads, (512,4): 2 blocks/CU, 128-reg budget, live ~60 (no spill, R5).
// R5 diagnosis: LDS-read-issue bound (30 b32/kh-tile). Now 15 wider reads:
// weights 3x b128 (float4 over m), x 6x (b64+b32).
__global__ __launch_bounds__(512, 4) void k_conv12(const float* __restrict__ gimg,
        const float* __restrict__ w0, const float* __restrict__ b0,
        const float* __restrict__ w1t, const float* __restrict__ b1,
        float* __restrict__ gout2) {
  __shared__ __align__(16) float simg[3456];
  __shared__ __align__(16) float sw0[288];
  __shared__ float sb0[32];
  __shared__ __align__(16) float sc1g[4 * 828];   // 4 ch x [23][36] (even rows)
  __shared__ __align__(16) float sw1g[4 * 9 * 64]; // [c4][9k][16ocq][4m]
  const int n = blockIdx.x, t = threadIdx.x;

  const float* gi = gimg + n * 3456;
  for (int k = t; k < 3456; k += 512) simg[k] = gi[k];
  if (t < 288) sw0[t] = w0[t];
  if (t >= 480) sb0[t - 480] = b0[t - 480];

  // thread = (ocq, g); oc in {ocq+16m}, sp = q*32+g
  const int ocq = t & 15, g = t >> 4;   // g in 0..31
  float acc[6][4];
  int rowb[6];
#pragma unroll
  for (int m = 0; m < 4; ++m) {
    float bb = b1[ocq + 16 * m];
#pragma unroll
    for (int q = 0; q < 6; ++q) acc[q][m] = bb;
  }
#pragma unroll
  for (int q = 0; q < 6; ++q) {
    int sp = q * 32 + g; if (sp > 186) sp = 186;
    int oh = sp / 17, ow = sp - oh * 17;
    rowb[q] = (2 * oh) * 36 + 2 * ow;
  }
  __syncthreads();

  for (int grp = 0; grp < 8; ++grp) {
    // stage w1 slice (contiguous in new layout: c in [4grp, 4grp+4))
    for (int k = t; k < 2304; k += 512) sw1g[k] = w1t[grp * 2304 + k];
    // conv1 for channels 4*grp .. 4*grp+3
    for (int idx = t; idx < 3220; idx += 512) {
      int c4 = idx / 805, sp = idx - c4 * 805;
      int oh = sp / 35, ow = sp - oh * 35;
      const float* ip = simg + (2 * oh) * 72 + 2 * ow;   // even -> 8B aligned
      const float* wp = sw0 + (grp * 4 + c4) * 9;
      float a = sb0[grp * 4 + c4];
#pragma unroll
      for (int kh = 0; kh < 3; ++kh) {
        float2 x01 = *(const float2*)(ip + kh * 72);
        float x2 = ip[kh * 72 + 2];
        a += x01.x * wp[kh * 3 + 0] + x01.y * wp[kh * 3 + 1] + x2 * wp[kh * 3 + 2];
      }
      sc1g[c4 * 828 + oh * 36 + ow] = fmaxf(a, 0.f);
    }
    __syncthreads();

#pragma unroll 1
    for (int c4 = 0; c4 < 4; ++c4) {
      const float* cb = sc1g + c4 * 828;
      const float4* wb4 = (const float4*)sw1g + c4 * 9 * 16;
#pragma unroll
      for (int kh = 0; kh < 3; ++kh) {
        float4 wv0 = wb4[(kh * 3 + 0) * 16 + ocq];
        float4 wv1 = wb4[(kh * 3 + 1) * 16 + ocq];
        float4 wv2 = wb4[(kh * 3 + 2) * 16 + ocq];
#pragma unroll
        for (int q = 0; q < 6; ++q) {
          const float* p = cb + rowb[q] + kh * 36;    // even -> 8B aligned
          float2 x01 = *(const float2*)p;
          float x2 = p[2];
          acc[q][0] += x01.x * wv0.x + x01.y * wv1.x + x2 * wv2.x;
          acc[q][1] += x01.x * wv0.y + x01.y * wv1.y + x2 * wv2.y;
          acc[q][2] += x01.x * wv0.z + x01.y * wv1.z + x2 * wv2.z;
          acc[q][3] += x01.x * wv0.w + x01.y * wv1.w + x2 * wv2.w;
        }
      }
    }
    __syncthreads();
  }

  float* go = gout2 + n * 11968;
#pragma unroll
  for (int q = 0; q < 6; ++q) {
    int sp = q * 32 + g;
    if (sp < 187)
#pragma unroll
      for (int m = 0; m < 4; ++m)
        go[sp * 64 + ocq + 16 * m] = fmaxf(acc[q][m], 0.f);
  }
}

// -------- conv3 + concat, one block per image, channel-sliced --------
// sin2g [16c][11h][18w] (even row stride -> contiguous 8B-aligned x-window).
// sw2g [16ocq][9k][16c][2m] padded to 290/ocq (290%32=2 -> 16 lanes,
// 16 distinct banks). LDS = (16*198 + 16*290)*4B = 31.2 KB -> 4 blocks/CU.
__global__ __launch_bounds__(256, 4) void k_conv3(const float* __restrict__ gout2,
        const float* __restrict__ w2t, const float* __restrict__ b2,
        const float* __restrict__ grel, float* __restrict__ gx) {
  __shared__ __align__(16) float sin2g[16 * 198];
  __shared__ __align__(16) float sw2g[16 * 290];
  const int n = blockIdx.x, t = threadIdx.x;
  const float* gi = gout2 + n * 11968;

  const int oc = t & 15, g = t >> 4;   // oc handles {oc, oc+16}; sp = q*16+g
  float acc[3][2];
  int rowb[3];
#pragma unroll
  for (int q = 0; q < 3; ++q) {
    acc[q][0] = b2[oc]; acc[q][1] = b2[oc + 16];
    int sp = q * 16 + g; if (sp > 39) sp = 39;
    int oh = sp >> 3, ow = sp & 7;
    rowb[q] = (2 * oh) * 18 + 2 * ow;   // [h][w] base, row stride 18 (even)
  }

  for (int grp = 0; grp < 4; ++grp) {
    // stage input slice: gi[sp*64 + grp*16 + c] -> sin2g[c*198 + h*18 + w]
    for (int idx = t; idx < 2992; idx += 256) {
      int sp = idx >> 4, c = idx & 15;
      int h = sp / 17, w = sp - h * 17;
      sin2g[c * 198 + h * 18 + w] = gi[sp * 64 + grp * 16 + c];
    }
    // stage weight slice: sw2g[ocq*290 + k*32 + cc2] <- w2t
    for (int idx = t; idx < 4608; idx += 256) {
      int ocq2 = idx / 288, r = idx - ocq2 * 288;   // r = k*32 + cc*2 + m
      int k = r >> 5;
      sw2g[ocq2 * 290 + r] = w2t[(ocq2 * 9 + k) * 128 + grp * 32 + (r & 31)];
    }
    __syncthreads();

    for (int c = 0; c < 16; ++c) {
      const float* cb = sin2g + c * 198;
      const float* wb = sw2g + oc * 290 + c * 2;
#pragma unroll
      for (int kh = 0; kh < 3; ++kh) {
        float2 wv0 = *(const float2*)(wb + (kh * 3 + 0) * 32);
        float2 wv1 = *(const float2*)(wb + (kh * 3 + 1) * 32);
        float2 wv2 = *(const float2*)(wb + (kh * 3 + 2) * 32);
#pragma unroll
        for (int q = 0; q < 3; ++q) {
          const float* p = cb + rowb[q] + kh * 18;   // even -> 8B aligned
          float2 x01 = *(const float2*)p;
          float x2 = p[2];
          acc[q][0] += x01.x * wv0.x + x01.y * wv1.x + x2 * wv2.x;
          acc[q][1] += x01.x * wv0.y + x01.y * wv1.y + x2 * wv2.y;
        }
      }
    }
    __syncthreads();
  }

  float* xo = gx + n * 1283;
#pragma unroll
  for (int q = 0; q < 3; ++q) {
    int sp = q * 16 + g;
    if (sp < 40) {
      xo[oc * 40 + sp]        = fmaxf(acc[q][0], 0.f);
      xo[(oc + 16) * 40 + sp] = fmaxf(acc[q][1], 0.f);
    }
  }
  if (t < 3) xo[1280 + t] = grel[n * 3 + t];
}

// -------- sensory synapse sums: 8 time-slots per block --------
__global__ __launch_bounds__(256) void k_sensory(const float* __restrict__ gx,
        const float* __restrict__ iw, const float* __restrict__ ib,
        const float* __restrict__ psig, const float* __restrict__ pmu,
        const float* __restrict__ pw, const float* __restrict__ pwe,
        float* __restrict__ wnum, float* __restrict__ wden) {
  __shared__ float xs[8 * 1283];
  const int t = threadIdx.x;
  const int bs0 = blockIdx.x * 8;
  for (int idx = t; idx < 8 * 1283; idx += 256) {
    int slot = idx / 1283, i = idx - slot * 1283;
    xs[idx] = gx[(bs0 + slot) * 1283 + i] * iw[i] + ib[i];
  }
  __syncthreads();
  const int w = t >> 6, l = t & 63;
  for (int jj = 0; jj < 12; ++jj) {
    int j = w * 12 + jj;
    const float* pa = psig + j * 1283;
    const float* pm = pmu + j * 1283;
    const float* pww = pw + j * 1283;
    const float* pe = pwe + j * 1283;
    float an[8], ad[8];
#pragma unroll
    for (int s2 = 0; s2 < 8; ++s2) { an[s2] = 0.f; ad[s2] = 0.f; }
    for (int i = l; i < 1283; i += 64) {
      float a = pa[i], m = pm[i], ww = pww[i], we = pe[i];
#pragma unroll
      for (int s2 = 0; s2 < 8; ++s2) {
        float sg = sigmoid_f((xs[s2 * 1283 + i] - m) * a);
        an[s2] += we * sg;
        ad[s2] += ww * sg;
      }
    }
#pragma unroll
    for (int off = 32; off; off >>= 1)
#pragma unroll
      for (int s2 = 0; s2 < 8; ++s2) {
        an[s2] += __shfl_xor(an[s2], off);
        ad[s2] += __shfl_xor(ad[s2], off);
      }
    if (l == 0) {
#pragma unroll
      for (int s2 = 0; s2 < 8; ++s2) {
        wnum[(bs0 + s2) * 48 + j] = an[s2];
        wden[(bs0 + s2) * 48 + j] = ad[s2];
      }
    }
  }
}

// -------- LTC scan: one block per batch, 48 posts x 8 pre-groups --------
// Params packed float4 (mu, sig, wm, wme): 1 b128 per (i,j) vs 4 b32.
__global__ __launch_bounds__(384) void k_scan(const float* __restrict__ gmu,
        const float* __restrict__ gsig, const float* __restrict__ wm,
        const float* __restrict__ wme, const float* __restrict__ wnum,
        const float* __restrict__ wden, const float* __restrict__ gleak,
        const float* __restrict__ vleak, const float* __restrict__ cm,
        const float* __restrict__ w_out, const float* __restrict__ b_out,
        const float* __restrict__ w_head, const float* __restrict__ b_head,
        float* __restrict__ out) {
  __shared__ float4 sp4[48 * 49];
  __shared__ float vbuf[2][48];
  __shared__ float m4[4];
  const int t = threadIdx.x, b = blockIdx.x;
  for (int idx = t; idx < 2304; idx += 384) {
    int i = idx / 48, jx = idx - i * 48;
    sp4[i * 49 + jx] = make_float4(gmu[idx], gsig[idx], wm[idx], wme[idx]);
  }
  if (t < 48) { vbuf[0][t] = 0.f; vbuf[1][t] = 0.f; }
  __syncthreads();

  const int j = t >> 3, g = t & 7;
  const float cmt = cm[j] * 6.f;
  const float gl = gleak[j];
  const float glv = gl * vleak[j];
  float psum = 0.f;
  const float* pn = wnum + b * 2304 + j;
  const float* pd = wden + b * 2304 + j;

  for (int s = 0; s < 48; ++s) {
    float wns = pn[s * 48], wds = pd[s * 48];
#pragma unroll 1
    for (int u = 0; u < 6; ++u) {
      int cur = u & 1;
      float an = 0.f, ad = 0.f;
#pragma unroll
      for (int q = 0; q < 6; ++q) {
        int i = g * 6 + q;
        float vi = vbuf[cur][i];
        float4 P = sp4[i * 49 + j];
        float sg = sigmoid_f((vi - P.x) * P.y);
        an += P.w * sg;
        ad += P.z * sg;
      }
      an += __shfl_xor(an, 1); ad += __shfl_xor(ad, 1);
      an += __shfl_xor(an, 2); ad += __shfl_xor(ad, 2);
      an += __shfl_xor(an, 4); ad += __shfl_xor(ad, 4);
      if (g == 0) {
        float vj = vbuf[cur][j];
        float num = cmt * vj + glv + an + wns;
        float den = cmt + gl + ad + wds + 1e-8f;
        vbuf[cur ^ 1][j] = num / den;
      }
      __syncthreads();
    }
    if (g == 0 && j < 4) psum += vbuf[0][j];
  }
  if (g == 0 && j < 4) m4[j] = psum * (1.f / 48.f) * w_out[j] + b_out[j];
  __syncthreads();
  if (t < 2) {
    float a = b_head[t];
#pragma unroll
    for (int jm = 0; jm < 4; ++jm) a += m4[jm] * w_head[jm * 2 + t];
    out[b * 2 + t] = tanhf(a);
  }
}

extern "C" void kernel_launch(void* const* d_in, const int* in_sizes, int n_in,
                              void* d_out, int out_size, void* d_ws, size_t ws_size,
                              hipStream_t stream) {
  const float* image   = (const float*)d_in[0];
  const float* rel     = (const float*)d_in[1];
  const float* w0      = (const float*)d_in[2];
  const float* b0      = (const float*)d_in[3];
  const float* w1      = (const float*)d_in[4];
  const float* b1      = (const float*)d_in[5];
  const float* w2      = (const float*)d_in[6];
  const float* b2      = (const float*)d_in[7];
  const float* iw      = (const float*)d_in[8];
  const float* ib      = (const float*)d_in[9];
  const float* gleak   = (const float*)d_in[10];
  const float* vleak   = (const float*)d_in[11];
  const float* cm      = (const float*)d_in[12];
  const float* sigma   = (const float*)d_in[13];
  const float* mu      = (const float*)d_in[14];
  const float* w_syn   = (const float*)d_in[15];
  const float* erev    = (const float*)d_in[16];
  const float* s_sigma = (const float*)d_in[17];
  const float* s_mu    = (const float*)d_in[18];
  const float* s_w     = (const float*)d_in[19];
  const float* s_erev  = (const float*)d_in[20];
  const float* w_out   = (const float*)d_in[21];
  const float* b_out   = (const float*)d_in[22];
  const float* w_head  = (const float*)d_in[23];
  const float* b_head  = (const float*)d_in[24];
  const int* syn_mask  = (const int*)d_in[25];
  const int* sens_mask = (const int*)d_in[26];
  float* ws  = (float*)d_ws;
  float* out = (float*)d_out;

  k_pre_sensory<<<(1283 * 48 + 255) / 256, 256, 0, stream>>>(
      s_sigma, s_mu, s_w, s_erev, sens_mask,
      ws + O_SSIG, ws + O_SMU, ws + O_SW, ws + O_SWE);
  k_pre_rec<<<9, 256, 0, stream>>>(w_syn, erev, syn_mask, ws + O_WM, ws + O_WME);
  k_pre_w<<<144, 256, 0, stream>>>(w1, w2, ws + O_W1T, ws + O_W2T);

  k_conv12<<<1536, 512, 0, stream>>>(image, w0, b0, ws + O_W1T, b1, ws + O_OUT2);
  k_conv3<<<1536, 256, 0, stream>>>(ws + O_OUT2, ws + O_W2T, b2, rel, ws + O_X);

  k_sensory<<<192, 256, 0, stream>>>(ws + O_X, iw, ib,
      ws + O_SSIG, ws + O_SMU, ws + O_SW, ws + O_SWE, ws + O_WNUM, ws + O_WDEN);

  k_scan<<<32, 384, 0, stream>>>(mu, sigma, ws + O_WM, ws + O_WME,
      ws + O_WNUM, ws + O_WDEN, gleak, vleak, cm,
      w_out, b_out, w_head, b_head, out);
}

// Round 7
// 665.805 us; speedup vs baseline: 5.7783x; 1.1283x over previous
//
#include <hip/hip_runtime.h>
#include <math.h>

#define DINL __device__ __forceinline__

// ---------------- geometry ----------------
// image: [1536][48][72]
// conv1: -> [32][23][35]  (805 spatial)
// conv2: -> [64][11][17]  (187 spatial), stored as [n][sp][oc]
// conv3: -> [32][5][8]    (40 spatial) -> feat 1280, + rel_pos 3 -> 1283
// LTC: UNITS=48, ODE_UNFOLDS=6, S=48, B=32

static constexpr int O_OUT2 = 0;                         // [1536][187][64]
static constexpr int O_X    = O_OUT2 + 1536 * 187 * 64;  // [1536][1283]
static constexpr int O_WNUM = O_X + 1536 * 1283;         // [1536][48]
static constexpr int O_WDEN = O_WNUM + 1536 * 48;
static constexpr int O_SP4  = O_WDEN + 1536 * 48;        // float4 [48][1283] (sig,mu,w,we)
static constexpr int O_WM   = O_SP4 + 4 * 48 * 1283;     // [48][48] w_syn*mask
static constexpr int O_WME  = O_WM + 48 * 48;            // [48][48] w_syn*mask*erev
static constexpr int O_W1T  = O_WME + 48 * 48;           // [c][9k][64oc] (R5 layout)
static constexpr int O_W2T  = O_W1T + 32 * 9 * 64;       // [ocq][k][c][2m] (R6 layout)

DINL float sigmoid_f(float z) {
  return __builtin_amdgcn_rcpf(1.f + __expf(-z));
}

// -------- fused pre-pass: sensory float4 pack + rec fold + weight repacks ----
// grid: [0,241) sensory, [241,250) rec, [250,394) weights
__global__ __launch_bounds__(256) void k_pre(
    const float* __restrict__ ssig, const float* __restrict__ smu,
    const float* __restrict__ sw, const float* __restrict__ serev,
    const int* __restrict__ smask,
    const float* __restrict__ w_syn, const float* __restrict__ erev,
    const int* __restrict__ syn_mask,
    const float* __restrict__ w1, const float* __restrict__ w2,
    float4* __restrict__ o_p4, float* __restrict__ o_wm, float* __restrict__ o_wme,
    float* __restrict__ w1t, float* __restrict__ w2t) {
  const int bid = blockIdx.x, t = threadIdx.x;
  if (bid < 241) {
    int idx = bid * 256 + t;
    if (idx < 61584) {
      int i = idx / 48, j = idx - i * 48;
      float m = (float)smask[idx];
      float w = sw[idx] * m;
      o_p4[j * 1283 + i] = make_float4(ssig[idx], smu[idx], w, w * serev[idx]);
    }
  } else if (bid < 250) {
    int idx = (bid - 241) * 256 + t;
    if (idx < 2304) {
      float wm = w_syn[idx] * (float)syn_mask[idx];
      o_wm[idx]  = wm;
      o_wme[idx] = wm * erev[idx];
    }
  } else {
    int idx = (bid - 250) * 256 + t;
    if (idx < 18432) {          // w1 [64oc][32c][9k] -> [c][9k][64oc]
      int oc = idx / 288;
      int rem = idx - oc * 288;
      int c = rem / 9, k = rem - c * 9;
      w1t[(c * 9 + k) * 64 + oc] = w1[idx];
    } else if (idx < 36864) {   // w2 [32oc][64c][9k] -> [ocq][9k][64c][2m]
      int i2 = idx - 18432;
      int oc = i2 / 576;
      int rem = i2 - oc * 576;
      int c = rem / 9, k = rem - c * 9;
      w2t[(((oc & 15) * 9 + k) * 64 + c) * 2 + (oc >> 4)] = w2[i2];
    }
  }
}

// -------- fused conv1 + conv2, one block per image, channel-sliced --------
// 512 threads, (512,4). R5 inner loop (scalar b32 weight reads, 60 VGPR,
// no spill) + float2 x-window only (+2 live regs). R6's 3x float4 weight
// regs caused scratch spill (WRITE_SIZE 72->129 MB) — do not reintroduce.
__global__ __launch_bounds__(512, 4) void k_conv12(const float* __restrict__ gimg,
        const float* __restrict__ w0, const float* __restrict__ b0,
        const float* __restrict__ w1t, const float* __restrict__ b1,
        float* __restrict__ gout2) {
  __shared__ __align__(16) float simg[3456];
  __shared__ __align__(16) float sw0[288];
  __shared__ float sb0[32];
  __shared__ __align__(16) float sc1g[4 * 828];   // 4 ch x [23][36] (even rows)
  __shared__ __align__(16) float sw1g[4 * 9 * 64]; // [c4][9k][64oc]
  const int n = blockIdx.x, t = threadIdx.x;

  const float* gi = gimg + n * 3456;
  for (int k = t; k < 3456; k += 512) simg[k] = gi[k];
  if (t < 288) sw0[t] = w0[t];
  if (t >= 480) sb0[t - 480] = b0[t - 480];

  // thread = (ocq, g); oc in {ocq+16m}, sp = q*32+g
  const int ocq = t & 15, g = t >> 4;   // g in 0..31
  float acc[6][4];
  int rowb[6];
#pragma unroll
  for (int m = 0; m < 4; ++m) {
    float bb = b1[ocq + 16 * m];
#pragma unroll
    for (int q = 0; q < 6; ++q) acc[q][m] = bb;
  }
#pragma unroll
  for (int q = 0; q < 6; ++q) {
    int sp = q * 32 + g; if (sp > 186) sp = 186;
    int oh = sp / 17, ow = sp - oh * 17;
    rowb[q] = (2 * oh) * 36 + 2 * ow;
  }
  __syncthreads();

  for (int grp = 0; grp < 8; ++grp) {
    // stage w1 slice [4c][9k][64oc] (contiguous)
    for (int k = t; k < 2304; k += 512) sw1g[k] = w1t[grp * 2304 + k];
    // conv1 for channels 4*grp .. 4*grp+3
    for (int idx = t; idx < 3220; idx += 512) {
      int c4 = idx / 805, sp = idx - c4 * 805;
      int oh = sp / 35, ow = sp - oh * 35;
      const float* ip = simg + (2 * oh) * 72 + 2 * ow;   // even -> 8B aligned
      const float* wp = sw0 + (grp * 4 + c4) * 9;
      float a = sb0[grp * 4 + c4];
#pragma unroll
      for (int kh = 0; kh < 3; ++kh) {
        float2 x01 = *(const float2*)(ip + kh * 72);
        float x2 = ip[kh * 72 + 2];
        a += x01.x * wp[kh * 3 + 0] + x01.y * wp[kh * 3 + 1] + x2 * wp[kh * 3 + 2];
      }
      sc1g[c4 * 828 + oh * 36 + ow] = fmaxf(a, 0.f);
    }
    __syncthreads();

#pragma unroll 1
    for (int c4 = 0; c4 < 4; ++c4) {
      const float* cb = sc1g + c4 * 828;
      const float* wb = sw1g + c4 * 576;
#pragma unroll
      for (int kh = 0; kh < 3; ++kh) {
        float wr[4][3];
#pragma unroll
        for (int kw = 0; kw < 3; ++kw)
#pragma unroll
          for (int m = 0; m < 4; ++m)
            wr[m][kw] = wb[(kh * 3 + kw) * 64 + ocq + 16 * m];
#pragma unroll
        for (int q = 0; q < 6; ++q) {
          const float* p = cb + rowb[q] + kh * 36;    // even -> 8B aligned
          float2 x01 = *(const float2*)p;
          float x2 = p[2];
#pragma unroll
          for (int m = 0; m < 4; ++m)
            acc[q][m] += x01.x * wr[m][0] + x01.y * wr[m][1] + x2 * wr[m][2];
        }
      }
    }
    __syncthreads();
  }

  float* go = gout2 + n * 11968;
#pragma unroll
  for (int q = 0; q < 6; ++q) {
    int sp = q * 32 + g;
    if (sp < 187)
#pragma unroll
      for (int m = 0; m < 4; ++m)
        go[sp * 64 + ocq + 16 * m] = fmaxf(acc[q][m], 0.f);
  }
}

// -------- conv3 + concat, one block per image, channel-sliced --------
// sin2g [16c][11h][18w] (even row stride -> 8B-aligned x-window).
// sw2g [16ocq][9k][16c][2m] padded to 290 (oc*290 mod 32 = oc*2 -> 16 banks).
__global__ __launch_bounds__(256, 4) void k_conv3(const float* __restrict__ gout2,
        const float* __restrict__ w2t, const float* __restrict__ b2,
        const float* __restrict__ grel, float* __restrict__ gx) {
  __shared__ __align__(16) float sin2g[16 * 198];
  __shared__ __align__(16) float sw2g[16 * 290];
  const int n = blockIdx.x, t = threadIdx.x;
  const float* gi = gout2 + n * 11968;

  const int oc = t & 15, g = t >> 4;   // oc handles {oc, oc+16}; sp = q*16+g
  float acc[3][2];
  int rowb[3];
#pragma unroll
  for (int q = 0; q < 3; ++q) {
    acc[q][0] = b2[oc]; acc[q][1] = b2[oc + 16];
    int sp = q * 16 + g; if (sp > 39) sp = 39;
    int oh = sp >> 3, ow = sp & 7;
    rowb[q] = (2 * oh) * 18 + 2 * ow;   // [h][w] base, row stride 18 (even)
  }

  for (int grp = 0; grp < 4; ++grp) {
    // stage input slice: gi[sp*64 + grp*16 + c] -> sin2g[c*198 + h*18 + w]
    for (int idx = t; idx < 2992; idx += 256) {
      int sp = idx >> 4, c = idx & 15;
      int h = sp / 17, w = sp - h * 17;
      sin2g[c * 198 + h * 18 + w] = gi[sp * 64 + grp * 16 + c];
    }
    // stage weight slice: sw2g[ocq*290 + k*32 + cc2] <- w2t
    for (int idx = t; idx < 4608; idx += 256) {
      int ocq2 = idx / 288, r = idx - ocq2 * 288;   // r = k*32 + cc*2 + m
      int k = r >> 5;
      sw2g[ocq2 * 290 + r] = w2t[(ocq2 * 9 + k) * 128 + grp * 32 + (r & 31)];
    }
    __syncthreads();

    for (int c = 0; c < 16; ++c) {
      const float* cb = sin2g + c * 198;
      const float* wb = sw2g + oc * 290 + c * 2;
#pragma unroll
      for (int kh = 0; kh < 3; ++kh) {
        float2 wv0 = *(const float2*)(wb + (kh * 3 + 0) * 32);
        float2 wv1 = *(const float2*)(wb + (kh * 3 + 1) * 32);
        float2 wv2 = *(const float2*)(wb + (kh * 3 + 2) * 32);
#pragma unroll
        for (int q = 0; q < 3; ++q) {
          const float* p = cb + rowb[q] + kh * 18;   // even -> 8B aligned
          float2 x01 = *(const float2*)p;
          float x2 = p[2];
          acc[q][0] += x01.x * wv0.x + x01.y * wv1.x + x2 * wv2.x;
          acc[q][1] += x01.x * wv0.y + x01.y * wv1.y + x2 * wv2.y;
        }
      }
    }
    __syncthreads();
  }

  float* xo = gx + n * 1283;
#pragma unroll
  for (int q = 0; q < 3; ++q) {
    int sp = q * 16 + g;
    if (sp < 40) {
      xo[oc * 40 + sp]        = fmaxf(acc[q][0], 0.f);
      xo[(oc + 16) * 40 + sp] = fmaxf(acc[q][1], 0.f);
    }
  }
  if (t < 3) xo[1280 + t] = grel[n * 3 + t];
}

// -------- sensory synapse sums: 4 time-slots x 24 j per block --------
// R6 version ran at 0.75 waves/SIMD chip-wide (192 blocks) — no latency
// hiding for the exp/rcp chains. Now: 768 blocks (3 waves/SIMD), params as
// ONE float4 load per synapse (was 4 b32).
__global__ __launch_bounds__(256) void k_sensory(const float* __restrict__ gx,
        const float* __restrict__ iw, const float* __restrict__ ib,
        const float4* __restrict__ p4,
        float* __restrict__ wnum, float* __restrict__ wden) {
  __shared__ float xs[4 * 1283];
  const int t = threadIdx.x, bid = blockIdx.x;
  const int bs0 = (bid >> 1) * 4;        // 4 time-slots
  const int jbase = (bid & 1) * 24;      // j-half
  for (int idx = t; idx < 4 * 1283; idx += 256) {
    int slot = idx / 1283, i = idx - slot * 1283;
    xs[idx] = gx[(bs0 + slot) * 1283 + i] * iw[i] + ib[i];
  }
  __syncthreads();
  const int w = t >> 6, l = t & 63;
  for (int jj = 0; jj < 6; ++jj) {
    int j = jbase + w * 6 + jj;
    const float4* pp = p4 + j * 1283;
    float an[4], ad[4];
#pragma unroll
    for (int s2 = 0; s2 < 4; ++s2) { an[s2] = 0.f; ad[s2] = 0.f; }
    for (int i = l; i < 1283; i += 64) {
      float4 P = pp[i];   // x=sig, y=mu, z=w, w=we
#pragma unroll
      for (int s2 = 0; s2 < 4; ++s2) {
        float sg = sigmoid_f((xs[s2 * 1283 + i] - P.y) * P.x);
        an[s2] += P.w * sg;
        ad[s2] += P.z * sg;
      }
    }
#pragma unroll
    for (int off = 32; off; off >>= 1)
#pragma unroll
      for (int s2 = 0; s2 < 4; ++s2) {
        an[s2] += __shfl_xor(an[s2], off);
        ad[s2] += __shfl_xor(ad[s2], off);
      }
    if (l == 0) {
#pragma unroll
      for (int s2 = 0; s2 < 4; ++s2) {
        wnum[(bs0 + s2) * 48 + j] = an[s2];
        wden[(bs0 + s2) * 48 + j] = ad[s2];
      }
    }
  }
}

// -------- LTC scan: one block per batch, 48 posts x 8 pre-groups --------
// Params packed float4 (mu, sig, wm, wme): 1 b128 per (i,j).
__global__ __launch_bounds__(384) void k_scan(const float* __restrict__ gmu,
        const float* __restrict__ gsig, const float* __restrict__ wm,
        const float* __restrict__ wme, const float* __restrict__ wnum,
        const float* __restrict__ wden, const float* __restrict__ gleak,
        const float* __restrict__ vleak, const float* __restrict__ cm,
        const float* __restrict__ w_out, const float* __restrict__ b_out,
        const float* __restrict__ w_head, const float* __restrict__ b_head,
        float* __restrict__ out) {
  __shared__ float4 sp4[48 * 49];
  __shared__ float vbuf[2][48];
  __shared__ float m4[4];
  const int t = threadIdx.x, b = blockIdx.x;
  for (int idx = t; idx < 2304; idx += 384) {
    int i = idx / 48, jx = idx - i * 48;
    sp4[i * 49 + jx] = make_float4(gmu[idx], gsig[idx], wm[idx], wme[idx]);
  }
  if (t < 48) { vbuf[0][t] = 0.f; vbuf[1][t] = 0.f; }
  __syncthreads();

  const int j = t >> 3, g = t & 7;
  const float cmt = cm[j] * 6.f;
  const float gl = gleak[j];
  const float glv = gl * vleak[j];
  float psum = 0.f;
  const float* pn = wnum + b * 2304 + j;
  const float* pd = wden + b * 2304 + j;

  for (int s = 0; s < 48; ++s) {
    float wns = pn[s * 48], wds = pd[s * 48];
#pragma unroll 1
    for (int u = 0; u < 6; ++u) {
      int cur = u & 1;
      float an = 0.f, ad = 0.f;
#pragma unroll
      for (int q = 0; q < 6; ++q) {
        int i = g * 6 + q;
        float vi = vbuf[cur][i];
        float4 P = sp4[i * 49 + j];
        float sg = sigmoid_f((vi - P.x) * P.y);
        an += P.w * sg;
        ad += P.z * sg;
      }
      an += __shfl_xor(an, 1); ad += __shfl_xor(ad, 1);
      an += __shfl_xor(an, 2); ad += __shfl_xor(ad, 2);
      an += __shfl_xor(an, 4); ad += __shfl_xor(ad, 4);
      if (g == 0) {
        float vj = vbuf[cur][j];
        float num = cmt * vj + glv + an + wns;
        float den = cmt + gl + ad + wds + 1e-8f;
        vbuf[cur ^ 1][j] = num / den;
      }
      __syncthreads();
    }
    if (g == 0 && j < 4) psum += vbuf[0][j];
  }
  if (g == 0 && j < 4) m4[j] = psum * (1.f / 48.f) * w_out[j] + b_out[j];
  __syncthreads();
  if (t < 2) {
    float a = b_head[t];
#pragma unroll
    for (int jm = 0; jm < 4; ++jm) a += m4[jm] * w_head[jm * 2 + t];
    out[b * 2 + t] = tanhf(a);
  }
}

extern "C" void kernel_launch(void* const* d_in, const int* in_sizes, int n_in,
                              void* d_out, int out_size, void* d_ws, size_t ws_size,
                              hipStream_t stream) {
  const float* image   = (const float*)d_in[0];
  const float* rel     = (const float*)d_in[1];
  const float* w0      = (const float*)d_in[2];
  const float* b0      = (const float*)d_in[3];
  const float* w1      = (const float*)d_in[4];
  const float* b1      = (const float*)d_in[5];
  const float* w2      = (const float*)d_in[6];
  const float* b2      = (const float*)d_in[7];
  const float* iw      = (const float*)d_in[8];
  const float* ib      = (const float*)d_in[9];
  const float* gleak   = (const float*)d_in[10];
  const float* vleak   = (const float*)d_in[11];
  const float* cm      = (const float*)d_in[12];
  const float* sigma   = (const float*)d_in[13];
  const float* mu      = (const float*)d_in[14];
  const float* w_syn   = (const float*)d_in[15];
  const float* erev    = (const float*)d_in[16];
  const float* s_sigma = (const float*)d_in[17];
  const float* s_mu    = (const float*)d_in[18];
  const float* s_w     = (const float*)d_in[19];
  const float* s_erev  = (const float*)d_in[20];
  const float* w_out   = (const float*)d_in[21];
  const float* b_out   = (const float*)d_in[22];
  const float* w_head  = (const float*)d_in[23];
  const float* b_head  = (const float*)d_in[24];
  const int* syn_mask  = (const int*)d_in[25];
  const int* sens_mask = (const int*)d_in[26];
  float* ws  = (float*)d_ws;
  float* out = (float*)d_out;

  k_pre<<<394, 256, 0, stream>>>(s_sigma, s_mu, s_w, s_erev, sens_mask,
      w_syn, erev, syn_mask, w1, w2,
      (float4*)(ws + O_SP4), ws + O_WM, ws + O_WME, ws + O_W1T, ws + O_W2T);

  k_conv12<<<1536, 512, 0, stream>>>(image, w0, b0, ws + O_W1T, b1, ws + O_OUT2);
  k_conv3<<<1536, 256, 0, stream>>>(ws + O_OUT2, ws + O_W2T, b2, rel, ws + O_X);

  k_sensory<<<768, 256, 0, stream>>>(ws + O_X, iw, ib,
      (const float4*)(ws + O_SP4), ws + O_WNUM, ws + O_WDEN);

  k_scan<<<32, 384, 0, stream>>>(mu, sigma, ws + O_WM, ws + O_WME,
      ws + O_WNUM, ws + O_WDEN, gleak, vleak, cm,
      w_out, b_out, w_head, b_head, out);
}

// Round 8
// 522.137 us; speedup vs baseline: 7.3682x; 1.2752x over previous
//
#include <hip/hip_runtime.h>
#include <math.h>

#define DINL __device__ __forceinline__

typedef __attribute__((ext_vector_type(8))) short short8;   // 8 bf16 (4 VGPR)
typedef __attribute__((ext_vector_type(4))) float f32x4;    // MFMA acc
typedef unsigned short ushortx;
typedef unsigned int uintx;

// ---------------- geometry ----------------
// image: [1536][48][72]
// conv1: -> [32][23][35]  (805 spatial)
// conv2: -> [64][11][17]  (187 spatial), stored as [n][sp][oc]  (MFMA, bf16 hi/lo x3)
// conv3: -> [32][5][8]    (40 spatial) -> feat 1280, + rel_pos 3 -> 1283
// LTC: UNITS=48, ODE_UNFOLDS=6, S=48, B=32

static constexpr int O_OUT2 = 0;                         // [1536][187][64]
static constexpr int O_X    = O_OUT2 + 1536 * 187 * 64;  // [1536][1283]
static constexpr int O_WNUM = O_X + 1536 * 1283;         // [1536][48]
static constexpr int O_WDEN = O_WNUM + 1536 * 48;
static constexpr int O_SP4  = O_WDEN + 1536 * 48;        // float4 [48][1283] (sig,mu,w,we)
static constexpr int O_WM   = O_SP4 + 4 * 48 * 1283;     // [48][48]
static constexpr int O_WME  = O_WM + 48 * 48;
static constexpr int O_W2T  = O_WME + 48 * 48;           // [ocq][k][c][2m] fp32 (conv3)
static constexpr int O_W1H  = O_W2T + 32 * 9 * 64;       // bf16-hi [9tap][64oc][32c] (18432 us = 9216 fl)
static constexpr int O_W1L  = O_W1H + 9216;              // bf16-lo  same

DINL float sigmoid_f(float z) {
  return __builtin_amdgcn_rcpf(1.f + __expf(-z));
}

DINL ushortx bf16_rne(float x) {        // round-to-nearest-even fp32->bf16 bits
  uintx u = __float_as_uint(x);
  return (ushortx)((u + 0x7FFFu + ((u >> 16) & 1u)) >> 16);
}

// -------- fused pre-pass: sensory pack + rec fold + w2 repack + w1 bf16 split
// grid: [0,241) sensory, [241,250) rec, [250,394) weights
__global__ __launch_bounds__(256) void k_pre(
    const float* __restrict__ ssig, const float* __restrict__ smu,
    const float* __restrict__ sw, const float* __restrict__ serev,
    const int* __restrict__ smask,
    const float* __restrict__ w_syn, const float* __restrict__ erev,
    const int* __restrict__ syn_mask,
    const float* __restrict__ w1, const float* __restrict__ w2,
    float4* __restrict__ o_p4, float* __restrict__ o_wm, float* __restrict__ o_wme,
    float* __restrict__ w2t, ushortx* __restrict__ w1h, ushortx* __restrict__ w1l) {
  const int bid = blockIdx.x, t = threadIdx.x;
  if (bid < 241) {
    int idx = bid * 256 + t;
    if (idx < 61584) {
      int i = idx / 48, j = idx - i * 48;
      float m = (float)smask[idx];
      float w = sw[idx] * m;
      o_p4[j * 1283 + i] = make_float4(ssig[idx], smu[idx], w, w * serev[idx]);
    }
  } else if (bid < 250) {
    int idx = (bid - 241) * 256 + t;
    if (idx < 2304) {
      float wm = w_syn[idx] * (float)syn_mask[idx];
      o_wm[idx]  = wm;
      o_wme[idx] = wm * erev[idx];
    }
  } else {
    int idx = (bid - 250) * 256 + t;
    if (idx < 18432) {          // w1 [64oc][32c][9k] -> bf16 hi/lo [k][oc][c]
      int oc = idx / 288;
      int rem = idx - oc * 288;
      int c = rem / 9, k = rem - c * 9;
      float v = w1[idx];
      ushortx h = bf16_rne(v);
      float hv = __uint_as_float(((uintx)h) << 16);
      ushortx l = bf16_rne(v - hv);
      int dst = (k * 64 + oc) * 32 + c;
      w1h[dst] = h;
      w1l[dst] = l;
    } else if (idx < 36864) {   // w2 [32oc][64c][9k] -> [ocq][9k][64c][2m]
      int i2 = idx - 18432;
      int oc = i2 / 576;
      int rem = i2 - oc * 576;
      int c = rem / 9, k = rem - c * 9;
      w2t[(((oc & 15) * 9 + k) * 64 + c) * 2 + (oc >> 4)] = w2[i2];
    }
  }
}

// -------- fused conv1 + conv2 (MFMA), one block per image --------
// Dynamic LDS 121088 B: c1 hi/lo planes [23][36][32ch] bf16 (frag-friendly:
// channel-innermost, 16B-aligned k-slices) + img buffer (reused as per-tap
// weight stage) + w0/b0. 512 thr = 8 waves; wave owns 2 Mtiles x 3 Ntiles
// (M=64oc -> 4 tiles, N=187sp pad 192 -> 12 tiles). Per tap: 1 MFMA K-step
// of 32 channels; 3 products (AhBh, AlBh, AhBl) give full fp32 accuracy.
__global__ __launch_bounds__(512) void k_conv12(const float* __restrict__ gimg,
        const float* __restrict__ w0, const float* __restrict__ b0,
        const ushortx* __restrict__ w1h, const ushortx* __restrict__ w1l,
        const float* __restrict__ b1, float* __restrict__ gout2) {
  extern __shared__ __align__(16) char dyn[];
  ushortx* c1h = (ushortx*)dyn;                 // 26496 us = 52992 B
  ushortx* c1l = c1h + 26496;                   // 52992 B
  float* smem_a = (float*)(c1l + 26496);        // 3456 fl (img, then wtap stage)
  float* sw0 = smem_a + 3456;                   // 288
  float* sb0 = sw0 + 288;                       // 32
  ushortx* swh = (ushortx*)smem_a;              // per-tap w hi [64oc][32c]
  ushortx* swl = swh + 2048;                    // per-tap w lo

  const int n = blockIdx.x, t = threadIdx.x;

  const float* gi = gimg + n * 3456;
  for (int k = t; k < 3456; k += 512) smem_a[k] = gi[k];
  if (t < 288) sw0[t] = w0[t];
  if (t >= 480) sb0[t - 480] = b0[t - 480];

  // per-wave MFMA geometry
  const int lane = t & 63, wid = t >> 6;
  const int r15 = lane & 15, kg = lane >> 4;
  const int mt0 = (wid & 1) * 2;        // Mtiles mt0, mt0+1
  const int nt0 = (wid >> 1) * 3;       // Ntiles nt0..nt0+2
  int bbase[3], spv[3];
#pragma unroll
  for (int ni = 0; ni < 3; ++ni) {
    int sp = (nt0 + ni) * 16 + r15;
    spv[ni] = sp;
    int spc = sp > 186 ? 186 : sp;
    int oh = spc / 17, ow = spc - oh * 17;
    bbase[ni] = ((2 * oh) * 36 + 2 * ow) * 32 + kg * 8;
  }
  int aoff0 = (mt0 * 16 + r15) * 32 + kg * 8;   // [oc][32c] ushort index
  float4 bb[2];
  bb[0] = *(const float4*)(b1 + mt0 * 16 + kg * 4);
  bb[1] = *(const float4*)(b1 + (mt0 + 1) * 16 + kg * 4);
  f32x4 acc[2][3];
#pragma unroll
  for (int mi = 0; mi < 2; ++mi)
#pragma unroll
    for (int ni = 0; ni < 3; ++ni) acc[mi][ni] = (f32x4)(0.f);

  __syncthreads();

  // conv1 -> transposed hi/lo bf16 planes [h][w][c]
  for (int idx = t; idx < 25760; idx += 512) {
    int c = idx & 31, sp = idx >> 5;            // sp < 805
    int oh = sp / 35, ow = sp - oh * 35;
    const float* ip = smem_a + (2 * oh) * 72 + 2 * ow;
    const float* wp = sw0 + c * 9;
    float a = sb0[c];
#pragma unroll
    for (int kh = 0; kh < 3; ++kh)
      a += ip[kh * 72 + 0] * wp[kh * 3 + 0] + ip[kh * 72 + 1] * wp[kh * 3 + 1]
         + ip[kh * 72 + 2] * wp[kh * 3 + 2];
    a = fmaxf(a, 0.f);
    ushortx h = bf16_rne(a);
    float hv = __uint_as_float(((uintx)h) << 16);
    ushortx l = bf16_rne(a - hv);
    int pos = (oh * 36 + ow) * 32 + c;
    c1h[pos] = h;
    c1l[pos] = l;
  }

  const uintx* gwh = (const uintx*)w1h;
  const uintx* gwl = (const uintx*)w1l;
  for (int tap = 0; tap < 9; ++tap) {
    __syncthreads();                            // conv1 / prev-tap reads done
    for (int k = t; k < 1024; k += 512) {       // stage tap weights (8 KB)
      ((uintx*)swh)[k] = gwh[tap * 1024 + k];
      ((uintx*)swl)[k] = gwl[tap * 1024 + k];
    }
    __syncthreads();
    const int kh = tap / 3, kw = tap - kh * 3;
    const int toff = (kh * 36 + kw) * 32;
    short8 ah[2], al[2];
    ah[0] = *(const short8*)(swh + aoff0);
    al[0] = *(const short8*)(swl + aoff0);
    ah[1] = *(const short8*)(swh + aoff0 + 512);
    al[1] = *(const short8*)(swl + aoff0 + 512);
#pragma unroll
    for (int ni = 0; ni < 3; ++ni) {
      short8 bh = *(const short8*)(c1h + bbase[ni] + toff);
      short8 bl = *(const short8*)(c1l + bbase[ni] + toff);
#pragma unroll
      for (int mi = 0; mi < 2; ++mi) {
        acc[mi][ni] = __builtin_amdgcn_mfma_f32_16x16x32_bf16(ah[mi], bh, acc[mi][ni], 0, 0, 0);
        acc[mi][ni] = __builtin_amdgcn_mfma_f32_16x16x32_bf16(al[mi], bh, acc[mi][ni], 0, 0, 0);
        acc[mi][ni] = __builtin_amdgcn_mfma_f32_16x16x32_bf16(ah[mi], bl, acc[mi][ni], 0, 0, 0);
      }
    }
  }

  // D: col(sp)=lane&15, row(oc)=kg*4+reg  -> float4 per (mi,ni)
  float* go = gout2 + n * 11968;
#pragma unroll
  for (int mi = 0; mi < 2; ++mi)
#pragma unroll
    for (int ni = 0; ni < 3; ++ni) {
      if (spv[ni] < 187) {
        float4 v;
        v.x = fmaxf(acc[mi][ni][0] + bb[mi].x, 0.f);
        v.y = fmaxf(acc[mi][ni][1] + bb[mi].y, 0.f);
        v.z = fmaxf(acc[mi][ni][2] + bb[mi].z, 0.f);
        v.w = fmaxf(acc[mi][ni][3] + bb[mi].w, 0.f);
        *(float4*)(go + spv[ni] * 64 + (mt0 + mi) * 16 + kg * 4) = v;
      }
    }
}

// -------- conv3 + concat, one block per image, channel-sliced (R7) --------
__global__ __launch_bounds__(256, 4) void k_conv3(const float* __restrict__ gout2,
        const float* __restrict__ w2t, const float* __restrict__ b2,
        const float* __restrict__ grel, float* __restrict__ gx) {
  __shared__ __align__(16) float sin2g[16 * 198];
  __shared__ __align__(16) float sw2g[16 * 290];
  const int n = blockIdx.x, t = threadIdx.x;
  const float* gi = gout2 + n * 11968;

  const int oc = t & 15, g = t >> 4;
  float acc[3][2];
  int rowb[3];
#pragma unroll
  for (int q = 0; q < 3; ++q) {
    acc[q][0] = b2[oc]; acc[q][1] = b2[oc + 16];
    int sp = q * 16 + g; if (sp > 39) sp = 39;
    int oh = sp >> 3, ow = sp & 7;
    rowb[q] = (2 * oh) * 18 + 2 * ow;
  }

  for (int grp = 0; grp < 4; ++grp) {
    for (int idx = t; idx < 2992; idx += 256) {
      int sp = idx >> 4, c = idx & 15;
      int h = sp / 17, w = sp - h * 17;
      sin2g[c * 198 + h * 18 + w] = gi[sp * 64 + grp * 16 + c];
    }
    for (int idx = t; idx < 4608; idx += 256) {
      int ocq2 = idx / 288, r = idx - ocq2 * 288;
      int k = r >> 5;
      sw2g[ocq2 * 290 + r] = w2t[(ocq2 * 9 + k) * 128 + grp * 32 + (r & 31)];
    }
    __syncthreads();

    for (int c = 0; c < 16; ++c) {
      const float* cb = sin2g + c * 198;
      const float* wb = sw2g + oc * 290 + c * 2;
#pragma unroll
      for (int kh = 0; kh < 3; ++kh) {
        float2 wv0 = *(const float2*)(wb + (kh * 3 + 0) * 32);
        float2 wv1 = *(const float2*)(wb + (kh * 3 + 1) * 32);
        float2 wv2 = *(const float2*)(wb + (kh * 3 + 2) * 32);
#pragma unroll
        for (int q = 0; q < 3; ++q) {
          const float* p = cb + rowb[q] + kh * 18;
          float2 x01 = *(const float2*)p;
          float x2 = p[2];
          acc[q][0] += x01.x * wv0.x + x01.y * wv1.x + x2 * wv2.x;
          acc[q][1] += x01.x * wv0.y + x01.y * wv1.y + x2 * wv2.y;
        }
      }
    }
    __syncthreads();
  }

  float* xo = gx + n * 1283;
#pragma unroll
  for (int q = 0; q < 3; ++q) {
    int sp = q * 16 + g;
    if (sp < 40) {
      xo[oc * 40 + sp]        = fmaxf(acc[q][0], 0.f);
      xo[(oc + 16) * 40 + sp] = fmaxf(acc[q][1], 0.f);
    }
  }
  if (t < 3) xo[1280 + t] = grel[n * 3 + t];
}

// -------- sensory synapse sums: 4 time-slots x 24 j per block (R7) --------
__global__ __launch_bounds__(256) void k_sensory(const float* __restrict__ gx,
        const float* __restrict__ iw, const float* __restrict__ ib,
        const float4* __restrict__ p4,
        float* __restrict__ wnum, float* __restrict__ wden) {
  __shared__ float xs[4 * 1283];
  const int t = threadIdx.x, bid = blockIdx.x;
  const int bs0 = (bid >> 1) * 4;
  const int jbase = (bid & 1) * 24;
  for (int idx = t; idx < 4 * 1283; idx += 256) {
    int slot = idx / 1283, i = idx - slot * 1283;
    xs[idx] = gx[(bs0 + slot) * 1283 + i] * iw[i] + ib[i];
  }
  __syncthreads();
  const int w = t >> 6, l = t & 63;
  for (int jj = 0; jj < 6; ++jj) {
    int j = jbase + w * 6 + jj;
    const float4* pp = p4 + j * 1283;
    float an[4], ad[4];
#pragma unroll
    for (int s2 = 0; s2 < 4; ++s2) { an[s2] = 0.f; ad[s2] = 0.f; }
    for (int i = l; i < 1283; i += 64) {
      float4 P = pp[i];
#pragma unroll
      for (int s2 = 0; s2 < 4; ++s2) {
        float sg = sigmoid_f((xs[s2 * 1283 + i] - P.y) * P.x);
        an[s2] += P.w * sg;
        ad[s2] += P.z * sg;
      }
    }
#pragma unroll
    for (int off = 32; off; off >>= 1)
#pragma unroll
      for (int s2 = 0; s2 < 4; ++s2) {
        an[s2] += __shfl_xor(an[s2], off);
        ad[s2] += __shfl_xor(ad[s2], off);
      }
    if (l == 0) {
#pragma unroll
      for (int s2 = 0; s2 < 4; ++s2) {
        wnum[(bs0 + s2) * 48 + j] = an[s2];
        wden[(bs0 + s2) * 48 + j] = ad[s2];
      }
    }
  }
}

// -------- LTC scan: one block per batch (R7) --------
__global__ __launch_bounds__(384) void k_scan(const float* __restrict__ gmu,
        const float* __restrict__ gsig, const float* __restrict__ wm,
        const float* __restrict__ wme, const float* __restrict__ wnum,
        const float* __restrict__ wden, const float* __restrict__ gleak,
        const float* __restrict__ vleak, const float* __restrict__ cm,
        const float* __restrict__ w_out, const float* __restrict__ b_out,
        const float* __restrict__ w_head, const float* __restrict__ b_head,
        float* __restrict__ out) {
  __shared__ float4 sp4[48 * 49];
  __shared__ float vbuf[2][48];
  __shared__ float m4[4];
  const int t = threadIdx.x, b = blockIdx.x;
  for (int idx = t; idx < 2304; idx += 384) {
    int i = idx / 48, jx = idx - i * 48;
    sp4[i * 49 + jx] = make_float4(gmu[idx], gsig[idx], wm[idx], wme[idx]);
  }
  if (t < 48) { vbuf[0][t] = 0.f; vbuf[1][t] = 0.f; }
  __syncthreads();

  const int j = t >> 3, g = t & 7;
  const float cmt = cm[j] * 6.f;
  const float gl = gleak[j];
  const float glv = gl * vleak[j];
  float psum = 0.f;
  const float* pn = wnum + b * 2304 + j;
  const float* pd = wden + b * 2304 + j;

  for (int s = 0; s < 48; ++s) {
    float wns = pn[s * 48], wds = pd[s * 48];
#pragma unroll 1
    for (int u = 0; u < 6; ++u) {
      int cur = u & 1;
      float an = 0.f, ad = 0.f;
#pragma unroll
      for (int q = 0; q < 6; ++q) {
        int i = g * 6 + q;
        float vi = vbuf[cur][i];
        float4 P = sp4[i * 49 + j];
        float sg = sigmoid_f((vi - P.x) * P.y);
        an += P.w * sg;
        ad += P.z * sg;
      }
      an += __shfl_xor(an, 1); ad += __shfl_xor(ad, 1);
      an += __shfl_xor(an, 2); ad += __shfl_xor(ad, 2);
      an += __shfl_xor(an, 4); ad += __shfl_xor(ad, 4);
      if (g == 0) {
        float vj = vbuf[cur][j];
        float num = cmt * vj + glv + an + wns;
        float den = cmt + gl + ad + wds + 1e-8f;
        vbuf[cur ^ 1][j] = num / den;
      }
      __syncthreads();
    }
    if (g == 0 && j < 4) psum += vbuf[0][j];
  }
  if (g == 0 && j < 4) m4[j] = psum * (1.f / 48.f) * w_out[j] + b_out[j];
  __syncthreads();
  if (t < 2) {
    float a = b_head[t];
#pragma unroll
    for (int jm = 0; jm < 4; ++jm) a += m4[jm] * w_head[jm * 2 + t];
    out[b * 2 + t] = tanhf(a);
  }
}

extern "C" void kernel_launch(void* const* d_in, const int* in_sizes, int n_in,
                              void* d_out, int out_size, void* d_ws, size_t ws_size,
                              hipStream_t stream) {
  const float* image   = (const float*)d_in[0];
  const float* rel     = (const float*)d_in[1];
  const float* w0      = (const float*)d_in[2];
  const float* b0      = (const float*)d_in[3];
  const float* w1      = (const float*)d_in[4];
  const float* b1      = (const float*)d_in[5];
  const float* w2      = (const float*)d_in[6];
  const float* b2      = (const float*)d_in[7];
  const float* iw      = (const float*)d_in[8];
  const float* ib      = (const float*)d_in[9];
  const float* gleak   = (const float*)d_in[10];
  const float* vleak   = (const float*)d_in[11];
  const float* cm      = (const float*)d_in[12];
  const float* sigma   = (const float*)d_in[13];
  const float* mu      = (const float*)d_in[14];
  const float* w_syn   = (const float*)d_in[15];
  const float* erev    = (const float*)d_in[16];
  const float* s_sigma = (const float*)d_in[17];
  const float* s_mu    = (const float*)d_in[18];
  const float* s_w     = (const float*)d_in[19];
  const float* s_erev  = (const float*)d_in[20];
  const float* w_out   = (const float*)d_in[21];
  const float* b_out   = (const float*)d_in[22];
  const float* w_head  = (const float*)d_in[23];
  const float* b_head  = (const float*)d_in[24];
  const int* syn_mask  = (const int*)d_in[25];
  const int* sens_mask = (const int*)d_in[26];
  float* ws  = (float*)d_ws;
  float* out = (float*)d_out;

  hipFuncSetAttribute((const void*)k_conv12,
                      hipFuncAttributeMaxDynamicSharedMemorySize, 131072);

  k_pre<<<394, 256, 0, stream>>>(s_sigma, s_mu, s_w, s_erev, sens_mask,
      w_syn, erev, syn_mask, w1, w2,
      (float4*)(ws + O_SP4), ws + O_WM, ws + O_WME, ws + O_W2T,
      (ushortx*)(ws + O_W1H), (ushortx*)(ws + O_W1L));

  k_conv12<<<1536, 512, 121088, stream>>>(image, w0, b0,
      (const ushortx*)(ws + O_W1H), (const ushortx*)(ws + O_W1L), b1, ws + O_OUT2);
  k_conv3<<<1536, 256, 0, stream>>>(ws + O_OUT2, ws + O_W2T, b2, rel, ws + O_X);

  k_sensory<<<768, 256, 0, stream>>>(ws + O_X, iw, ib,
      (const float4*)(ws + O_SP4), ws + O_WNUM, ws + O_WDEN);

  k_scan<<<32, 384, 0, stream>>>(mu, sigma, ws + O_WM, ws + O_WME,
      ws + O_WNUM, ws + O_WDEN, gleak, vleak, cm,
      w_out, b_out, w_head, b_head, out);
}

// Round 9
// 512.033 us; speedup vs baseline: 7.5136x; 1.0197x over previous
//
#include <hip/hip_runtime.h>
#include <math.h>

#define DINL __device__ __forceinline__

typedef __attribute__((ext_vector_type(8))) short short8;   // 8 bf16 (4 VGPR)
typedef __attribute__((ext_vector_type(4))) float f32x4;    // MFMA acc
typedef unsigned short ushortx;
typedef unsigned int uintx;

// ---------------- geometry ----------------
// image: [1536][48][72]
// conv1: -> [32][23][35]  (805 spatial)
// conv2: -> [64][11][17]  (187 spatial), stored as [n][sp][oc]  (MFMA, bf16 hi/lo x3)
// conv3: -> [32][5][8]    (40 spatial) -> feat 1280, + rel_pos 3 -> 1283
// LTC: UNITS=48, ODE_UNFOLDS=6, S=48, B=32

static constexpr int O_OUT2 = 0;                         // [1536][187][64]
static constexpr int O_X    = O_OUT2 + 1536 * 187 * 64;  // [1536][1283]
static constexpr int O_WNUM = O_X + 1536 * 1283;         // [1536][48]
static constexpr int O_WDEN = O_WNUM + 1536 * 48;
static constexpr int O_SP4  = O_WDEN + 1536 * 48;        // float4 [48][1283] (sig,mu,w,we)
static constexpr int O_WM   = O_SP4 + 4 * 48 * 1283;     // (unused, kept for layout)
static constexpr int O_WME  = O_WM + 48 * 48;
static constexpr int O_W2T  = O_WME + 48 * 48;           // [ocq][k][c][2m] fp32 (conv3)
static constexpr int O_W1H  = O_W2T + 32 * 9 * 64;       // bf16-hi [9tap][64oc][32c]
static constexpr int O_W1L  = O_W1H + 9216;              // bf16-lo
static constexpr int O_R4   = O_W1L + 9216;              // float4 [48i][48j] (mu,sig,wm,wme)

DINL float sigmoid_f(float z) {
  return __builtin_amdgcn_rcpf(1.f + __expf(-z));
}

DINL ushortx bf16_rne(float x) {        // round-to-nearest-even fp32->bf16 bits
  uintx u = __float_as_uint(x);
  return (ushortx)((u + 0x7FFFu + ((u >> 16) & 1u)) >> 16);
}

// -------- fused pre-pass: sensory pack + rec float4 pack + w2 repack + w1 split
// grid: [0,241) sensory, [241,250) rec, [250,394) weights
__global__ __launch_bounds__(256) void k_pre(
    const float* __restrict__ ssig, const float* __restrict__ smu,
    const float* __restrict__ sw, const float* __restrict__ serev,
    const int* __restrict__ smask,
    const float* __restrict__ w_syn, const float* __restrict__ erev,
    const int* __restrict__ syn_mask,
    const float* __restrict__ gmu, const float* __restrict__ gsig,
    const float* __restrict__ w1, const float* __restrict__ w2,
    float4* __restrict__ o_p4, float4* __restrict__ o_r4,
    float* __restrict__ w2t, ushortx* __restrict__ w1h, ushortx* __restrict__ w1l) {
  const int bid = blockIdx.x, t = threadIdx.x;
  if (bid < 241) {
    int idx = bid * 256 + t;
    if (idx < 61584) {
      int i = idx / 48, j = idx - i * 48;
      float m = (float)smask[idx];
      float w = sw[idx] * m;
      o_p4[j * 1283 + i] = make_float4(ssig[idx], smu[idx], w, w * serev[idx]);
    }
  } else if (bid < 250) {
    int idx = (bid - 241) * 256 + t;
    if (idx < 2304) {
      float wm = w_syn[idx] * (float)syn_mask[idx];
      o_r4[idx] = make_float4(gmu[idx], gsig[idx], wm, wm * erev[idx]);
    }
  } else {
    int idx = (bid - 250) * 256 + t;
    if (idx < 18432) {          // w1 [64oc][32c][9k] -> bf16 hi/lo [k][oc][c]
      int oc = idx / 288;
      int rem = idx - oc * 288;
      int c = rem / 9, k = rem - c * 9;
      float v = w1[idx];
      ushortx h = bf16_rne(v);
      float hv = __uint_as_float(((uintx)h) << 16);
      ushortx l = bf16_rne(v - hv);
      int dst = (k * 64 + oc) * 32 + c;
      w1h[dst] = h;
      w1l[dst] = l;
    } else if (idx < 36864) {   // w2 [32oc][64c][9k] -> [ocq][9k][64c][2m]
      int i2 = idx - 18432;
      int oc = i2 / 576;
      int rem = i2 - oc * 576;
      int c = rem / 9, k = rem - c * 9;
      w2t[(((oc & 15) * 9 + k) * 64 + c) * 2 + (oc >> 4)] = w2[i2];
    }
  }
}

// -------- fused conv1 + conv2 (MFMA), one block per image (R8, proven) -----
__global__ __launch_bounds__(512) void k_conv12(const float* __restrict__ gimg,
        const float* __restrict__ w0, const float* __restrict__ b0,
        const ushortx* __restrict__ w1h, const ushortx* __restrict__ w1l,
        const float* __restrict__ b1, float* __restrict__ gout2) {
  extern __shared__ __align__(16) char dyn[];
  ushortx* c1h = (ushortx*)dyn;                 // 52992 B
  ushortx* c1l = c1h + 26496;                   // 52992 B
  float* smem_a = (float*)(c1l + 26496);        // 3456 fl (img, then wtap stage)
  float* sw0 = smem_a + 3456;                   // 288
  float* sb0 = sw0 + 288;                       // 32
  ushortx* swh = (ushortx*)smem_a;              // per-tap w hi [64oc][32c]
  ushortx* swl = swh + 2048;                    // per-tap w lo

  const int n = blockIdx.x, t = threadIdx.x;

  const float* gi = gimg + n * 3456;
  for (int k = t; k < 3456; k += 512) smem_a[k] = gi[k];
  if (t < 288) sw0[t] = w0[t];
  if (t >= 480) sb0[t - 480] = b0[t - 480];

  const int lane = t & 63, wid = t >> 6;
  const int r15 = lane & 15, kg = lane >> 4;
  const int mt0 = (wid & 1) * 2;
  const int nt0 = (wid >> 1) * 3;
  int bbase[3], spv[3];
#pragma unroll
  for (int ni = 0; ni < 3; ++ni) {
    int sp = (nt0 + ni) * 16 + r15;
    spv[ni] = sp;
    int spc = sp > 186 ? 186 : sp;
    int oh = spc / 17, ow = spc - oh * 17;
    bbase[ni] = ((2 * oh) * 36 + 2 * ow) * 32 + kg * 8;
  }
  int aoff0 = (mt0 * 16 + r15) * 32 + kg * 8;
  float4 bb[2];
  bb[0] = *(const float4*)(b1 + mt0 * 16 + kg * 4);
  bb[1] = *(const float4*)(b1 + (mt0 + 1) * 16 + kg * 4);
  f32x4 acc[2][3];
#pragma unroll
  for (int mi = 0; mi < 2; ++mi)
#pragma unroll
    for (int ni = 0; ni < 3; ++ni) acc[mi][ni] = (f32x4)(0.f);

  __syncthreads();

  for (int idx = t; idx < 25760; idx += 512) {
    int c = idx & 31, sp = idx >> 5;
    int oh = sp / 35, ow = sp - oh * 35;
    const float* ip = smem_a + (2 * oh) * 72 + 2 * ow;
    const float* wp = sw0 + c * 9;
    float a = sb0[c];
#pragma unroll
    for (int kh = 0; kh < 3; ++kh)
      a += ip[kh * 72 + 0] * wp[kh * 3 + 0] + ip[kh * 72 + 1] * wp[kh * 3 + 1]
         + ip[kh * 72 + 2] * wp[kh * 3 + 2];
    a = fmaxf(a, 0.f);
    ushortx h = bf16_rne(a);
    float hv = __uint_as_float(((uintx)h) << 16);
    ushortx l = bf16_rne(a - hv);
    int pos = (oh * 36 + ow) * 32 + c;
    c1h[pos] = h;
    c1l[pos] = l;
  }

  const uintx* gwh = (const uintx*)w1h;
  const uintx* gwl = (const uintx*)w1l;
  for (int tap = 0; tap < 9; ++tap) {
    __syncthreads();
    for (int k = t; k < 1024; k += 512) {
      ((uintx*)swh)[k] = gwh[tap * 1024 + k];
      ((uintx*)swl)[k] = gwl[tap * 1024 + k];
    }
    __syncthreads();
    const int kh = tap / 3, kw = tap - kh * 3;
    const int toff = (kh * 36 + kw) * 32;
    short8 ah[2], al[2];
    ah[0] = *(const short8*)(swh + aoff0);
    al[0] = *(const short8*)(swl + aoff0);
    ah[1] = *(const short8*)(swh + aoff0 + 512);
    al[1] = *(const short8*)(swl + aoff0 + 512);
#pragma unroll
    for (int ni = 0; ni < 3; ++ni) {
      short8 bh = *(const short8*)(c1h + bbase[ni] + toff);
      short8 bl = *(const short8*)(c1l + bbase[ni] + toff);
#pragma unroll
      for (int mi = 0; mi < 2; ++mi) {
        acc[mi][ni] = __builtin_amdgcn_mfma_f32_16x16x32_bf16(ah[mi], bh, acc[mi][ni], 0, 0, 0);
        acc[mi][ni] = __builtin_amdgcn_mfma_f32_16x16x32_bf16(al[mi], bh, acc[mi][ni], 0, 0, 0);
        acc[mi][ni] = __builtin_amdgcn_mfma_f32_16x16x32_bf16(ah[mi], bl, acc[mi][ni], 0, 0, 0);
      }
    }
  }

  float* go = gout2 + n * 11968;
#pragma unroll
  for (int mi = 0; mi < 2; ++mi)
#pragma unroll
    for (int ni = 0; ni < 3; ++ni) {
      if (spv[ni] < 187) {
        float4 v;
        v.x = fmaxf(acc[mi][ni][0] + bb[mi].x, 0.f);
        v.y = fmaxf(acc[mi][ni][1] + bb[mi].y, 0.f);
        v.z = fmaxf(acc[mi][ni][2] + bb[mi].z, 0.f);
        v.w = fmaxf(acc[mi][ni][3] + bb[mi].w, 0.f);
        *(float4*)(go + spv[ni] * 64 + (mt0 + mi) * 16 + kg * 4) = v;
      }
    }
}

// -------- conv3 + concat, one block per image, channel-sliced (R7) --------
__global__ __launch_bounds__(256, 4) void k_conv3(const float* __restrict__ gout2,
        const float* __restrict__ w2t, const float* __restrict__ b2,
        const float* __restrict__ grel, float* __restrict__ gx) {
  __shared__ __align__(16) float sin2g[16 * 198];
  __shared__ __align__(16) float sw2g[16 * 290];
  const int n = blockIdx.x, t = threadIdx.x;
  const float* gi = gout2 + n * 11968;

  const int oc = t & 15, g = t >> 4;
  float acc[3][2];
  int rowb[3];
#pragma unroll
  for (int q = 0; q < 3; ++q) {
    acc[q][0] = b2[oc]; acc[q][1] = b2[oc + 16];
    int sp = q * 16 + g; if (sp > 39) sp = 39;
    int oh = sp >> 3, ow = sp & 7;
    rowb[q] = (2 * oh) * 18 + 2 * ow;
  }

  for (int grp = 0; grp < 4; ++grp) {
    for (int idx = t; idx < 2992; idx += 256) {
      int sp = idx >> 4, c = idx & 15;
      int h = sp / 17, w = sp - h * 17;
      sin2g[c * 198 + h * 18 + w] = gi[sp * 64 + grp * 16 + c];
    }
    for (int idx = t; idx < 4608; idx += 256) {
      int ocq2 = idx / 288, r = idx - ocq2 * 288;
      int k = r >> 5;
      sw2g[ocq2 * 290 + r] = w2t[(ocq2 * 9 + k) * 128 + grp * 32 + (r & 31)];
    }
    __syncthreads();

    for (int c = 0; c < 16; ++c) {
      const float* cb = sin2g + c * 198;
      const float* wb = sw2g + oc * 290 + c * 2;
#pragma unroll
      for (int kh = 0; kh < 3; ++kh) {
        float2 wv0 = *(const float2*)(wb + (kh * 3 + 0) * 32);
        float2 wv1 = *(const float2*)(wb + (kh * 3 + 1) * 32);
        float2 wv2 = *(const float2*)(wb + (kh * 3 + 2) * 32);
#pragma unroll
        for (int q = 0; q < 3; ++q) {
          const float* p = cb + rowb[q] + kh * 18;
          float2 x01 = *(const float2*)p;
          float x2 = p[2];
          acc[q][0] += x01.x * wv0.x + x01.y * wv1.x + x2 * wv2.x;
          acc[q][1] += x01.x * wv0.y + x01.y * wv1.y + x2 * wv2.y;
        }
      }
    }
    __syncthreads();
  }

  float* xo = gx + n * 1283;
#pragma unroll
  for (int q = 0; q < 3; ++q) {
    int sp = q * 16 + g;
    if (sp < 40) {
      xo[oc * 40 + sp]        = fmaxf(acc[q][0], 0.f);
      xo[(oc + 16) * 40 + sp] = fmaxf(acc[q][1], 0.f);
    }
  }
  if (t < 3) xo[1280 + t] = grel[n * 3 + t];
}

// -------- sensory synapse sums: 4 time-slots x 24 j per block (R7) --------
__global__ __launch_bounds__(256) void k_sensory(const float* __restrict__ gx,
        const float* __restrict__ iw, const float* __restrict__ ib,
        const float4* __restrict__ p4,
        float* __restrict__ wnum, float* __restrict__ wden) {
  __shared__ float xs[4 * 1283];
  const int t = threadIdx.x, bid = blockIdx.x;
  const int bs0 = (bid >> 1) * 4;
  const int jbase = (bid & 1) * 24;
  for (int idx = t; idx < 4 * 1283; idx += 256) {
    int slot = idx / 1283, i = idx - slot * 1283;
    xs[idx] = gx[(bs0 + slot) * 1283 + i] * iw[i] + ib[i];
  }
  __syncthreads();
  const int w = t >> 6, l = t & 63;
  for (int jj = 0; jj < 6; ++jj) {
    int j = jbase + w * 6 + jj;
    const float4* pp = p4 + j * 1283;
    float an[4], ad[4];
#pragma unroll
    for (int s2 = 0; s2 < 4; ++s2) { an[s2] = 0.f; ad[s2] = 0.f; }
    for (int i = l; i < 1283; i += 64) {
      float4 P = pp[i];
#pragma unroll
      for (int s2 = 0; s2 < 4; ++s2) {
        float sg = sigmoid_f((xs[s2 * 1283 + i] - P.y) * P.x);
        an[s2] += P.w * sg;
        ad[s2] += P.z * sg;
      }
    }
#pragma unroll
    for (int off = 32; off; off >>= 1)
#pragma unroll
      for (int s2 = 0; s2 < 4; ++s2) {
        an[s2] += __shfl_xor(an[s2], off);
        ad[s2] += __shfl_xor(ad[s2], off);
      }
    if (l == 0) {
#pragma unroll
      for (int s2 = 0; s2 < 4; ++s2) {
        wnum[(bs0 + s2) * 48 + j] = an[s2];
        wden[(bs0 + s2) * 48 + j] = ad[s2];
      }
    }
  }
}

// -------- LTC scan: 1 block/batch, 192 thr (3 waves), params IN REGISTERS --
// thread (j = t>>2, g = t&3): post j, pre-group g of 12. P[12] float4 = 48
// VGPR loaded ONCE (time-invariant) — zero per-unfold param LDS traffic.
// v read as 3 ds_read_b128 broadcasts; 2-round 4-lane shfl reduce; double-
// buffered v -> ONE barrier per unfold (write goes to other buffer).
__global__ __launch_bounds__(192) void k_scan(const float4* __restrict__ r4,
        const float* __restrict__ wnum, const float* __restrict__ wden,
        const float* __restrict__ gleak, const float* __restrict__ vleak,
        const float* __restrict__ cm,
        const float* __restrict__ w_out, const float* __restrict__ b_out,
        const float* __restrict__ w_head, const float* __restrict__ b_head,
        float* __restrict__ out) {
  __shared__ float swn[48 * 48], swd[48 * 48];
  __shared__ __align__(16) float vbuf[2][48];
  __shared__ float m4[4];
  const int t = threadIdx.x, b = blockIdx.x;
  const int j = t >> 2, g = t & 3;

  const float* gn = wnum + b * 2304;
  const float* gd = wden + b * 2304;
  for (int k = t; k < 2304; k += 192) { swn[k] = gn[k]; swd[k] = gd[k]; }

  float4 P[12];
#pragma unroll
  for (int q = 0; q < 12; ++q) P[q] = r4[(g * 12 + q) * 48 + j];

  const float cmt = cm[j] * 6.f;
  const float gl = gleak[j];
  const float glv = gl * vleak[j];
  if (t < 48) { vbuf[0][t] = 0.f; vbuf[1][t] = 0.f; }
  float psum = 0.f;
  __syncthreads();

  int cur = 0;
  for (int s = 0; s < 48; ++s) {
    float wns = swn[s * 48 + j], wds = swd[s * 48 + j];
#pragma unroll 1
    for (int u = 0; u < 6; ++u) {
      const float4* vb4 = (const float4*)&vbuf[cur][g * 12];
      float4 va = vb4[0], vb = vb4[1], vc = vb4[2];
      float vv[12] = {va.x, va.y, va.z, va.w, vb.x, vb.y, vb.z, vb.w,
                      vc.x, vc.y, vc.z, vc.w};
      float an = 0.f, ad = 0.f;
#pragma unroll
      for (int q = 0; q < 12; ++q) {
        float sg = sigmoid_f((vv[q] - P[q].x) * P[q].y);
        an += P[q].w * sg;
        ad += P[q].z * sg;
      }
      an += __shfl_xor(an, 1); ad += __shfl_xor(ad, 1);
      an += __shfl_xor(an, 2); ad += __shfl_xor(ad, 2);
      if (g == 0) {
        float vj = vbuf[cur][j];
        float num = cmt * vj + glv + an + wns;
        float den = cmt + gl + ad + wds + 1e-8f;
        vbuf[cur ^ 1][j] = num / den;
      }
      __syncthreads();
      cur ^= 1;
    }
    if (g == 0 && j < 4) psum += vbuf[cur][j];
  }
  if (g == 0 && j < 4) m4[j] = psum * (1.f / 48.f) * w_out[j] + b_out[j];
  __syncthreads();
  if (t < 2) {
    float a = b_head[t];
#pragma unroll
    for (int jm = 0; jm < 4; ++jm) a += m4[jm] * w_head[jm * 2 + t];
    out[b * 2 + t] = tanhf(a);
  }
}

extern "C" void kernel_launch(void* const* d_in, const int* in_sizes, int n_in,
                              void* d_out, int out_size, void* d_ws, size_t ws_size,
                              hipStream_t stream) {
  const float* image   = (const float*)d_in[0];
  const float* rel     = (const float*)d_in[1];
  const float* w0      = (const float*)d_in[2];
  const float* b0      = (const float*)d_in[3];
  const float* w1      = (const float*)d_in[4];
  const float* b1      = (const float*)d_in[5];
  const float* w2      = (const float*)d_in[6];
  const float* b2      = (const float*)d_in[7];
  const float* iw      = (const float*)d_in[8];
  const float* ib      = (const float*)d_in[9];
  const float* gleak   = (const float*)d_in[10];
  const float* vleak   = (const float*)d_in[11];
  const float* cm      = (const float*)d_in[12];
  const float* sigma   = (const float*)d_in[13];
  const float* mu      = (const float*)d_in[14];
  const float* w_syn   = (const float*)d_in[15];
  const float* erev    = (const float*)d_in[16];
  const float* s_sigma = (const float*)d_in[17];
  const float* s_mu    = (const float*)d_in[18];
  const float* s_w     = (const float*)d_in[19];
  const float* s_erev  = (const float*)d_in[20];
  const float* w_out   = (const float*)d_in[21];
  const float* b_out   = (const float*)d_in[22];
  const float* w_head  = (const float*)d_in[23];
  const float* b_head  = (const float*)d_in[24];
  const int* syn_mask  = (const int*)d_in[25];
  const int* sens_mask = (const int*)d_in[26];
  float* ws  = (float*)d_ws;
  float* out = (float*)d_out;

  hipFuncSetAttribute((const void*)k_conv12,
                      hipFuncAttributeMaxDynamicSharedMemorySize, 131072);

  k_pre<<<394, 256, 0, stream>>>(s_sigma, s_mu, s_w, s_erev, sens_mask,
      w_syn, erev, syn_mask, mu, sigma, w1, w2,
      (float4*)(ws + O_SP4), (float4*)(ws + O_R4), ws + O_W2T,
      (ushortx*)(ws + O_W1H), (ushortx*)(ws + O_W1L));

  k_conv12<<<1536, 512, 121088, stream>>>(image, w0, b0,
      (const ushortx*)(ws + O_W1H), (const ushortx*)(ws + O_W1L), b1, ws + O_OUT2);
  k_conv3<<<1536, 256, 0, stream>>>(ws + O_OUT2, ws + O_W2T, b2, rel, ws + O_X);

  k_sensory<<<768, 256, 0, stream>>>(ws + O_X, iw, ib,
      (const float4*)(ws + O_SP4), ws + O_WNUM, ws + O_WDEN);

  k_scan<<<32, 192, 0, stream>>>((const float4*)(ws + O_R4),
      ws + O_WNUM, ws + O_WDEN, gleak, vleak, cm,
      w_out, b_out, w_head, b_head, out);
}